// Round 10
// baseline (501.294 us; speedup 1.0000x reference)
//
#include <hip/hip_runtime.h>

// ---------------------------------------------------------------------------
// ACBlock: BN1+ReLU -> Performer attention -> +x -> BN2+ReLU -> conv3x3 -> +x
// B=16 C=256 H=W=56  S=3136 tokens/batch, NTOK=50176, heads=8, d=32, m=110
// Round 15: FIX batch-offset bug in qkv epilogues (token0 vs s0): q/k/v
// row stores must use batch-local s0 = token0 - bb*SDIM. (Round-13's q/k
// epilogue silently scrambled head planes for bb>=1 — masked because
// near-uniform attention; round-14's v epilogue made it visible.)
// Keeps: attn grid-512 split, v LDS-transpose epilogue, ctx fusion,
// bn2-stats fusion, round-1 conv shape.
// ---------------------------------------------------------------------------

typedef short short8 __attribute__((ext_vector_type(8)));
typedef float f32x4 __attribute__((ext_vector_type(4)));

#define DEVI static __device__ __forceinline__

#define CDIM 256
#define SDIM 3136
#define NTOK 50176
#define NHEAD 8
#define DHEAD 32
#define MFEAT 110
#define NORMC 0.42044820762685725f  // 32^-0.25
#define NPIX 50176.0f

DEVI unsigned short f2bf(float f) {
  union { float f; unsigned u; } v; v.f = f;
  unsigned r = v.u + 0x7fffu + ((v.u >> 16) & 1u);
  return (unsigned short)(r >> 16);
}

DEVI float bf2f(short h) {
  union { unsigned u; float f; } v;
  v.u = ((unsigned)(unsigned short)h) << 16;
  return v.f;
}

DEVI f32x4 mfma16(short8 a, short8 b, f32x4 c) {
  return __builtin_amdgcn_mfma_f32_16x16x32_bf16(a, b, c, 0, 0, 0);
}

DEVI unsigned long long pack4(const unsigned short* h) {
  return (unsigned long long)(h[0] | ((unsigned)h[1] << 16)) |
         ((unsigned long long)(h[2] | ((unsigned)h[3] << 16)) << 32);
}

// ---------------------------------------------------------------------------
__global__ void zero_kernel(float* p, int n) {
  for (int i = blockIdx.x * blockDim.x + threadIdx.x; i < n; i += gridDim.x * blockDim.x)
    p[i] = 0.f;
}

// Fragment-major packed B operands.
// Layout: packed[(ks*16 + nf)*512 + lane*8 + j] = B[n = nf*16 + (lane&15)]
//                                                  [k = ks*32 + (lane>>4)*8 + j]
__global__ void prep_kernel(const float* __restrict__ Wq, const float* __restrict__ Wk,
                            const float* __restrict__ Wv, const float* __restrict__ Wo,
                            const float* __restrict__ proj, const float* __restrict__ conv_w,
                            short* __restrict__ Bqkv, short* __restrict__ WoT,
                            short* __restrict__ Bconv, short* __restrict__ projb) {
  const int t0 = blockIdx.x * blockDim.x + threadIdx.x;
  const int stride = gridDim.x * blockDim.x;
  for (int idx = t0; idx < 3 * 65536; idx += stride) {
    const int sel = idx >> 16, r = idx & 65535;
    const int ks = r >> 13, nf = (r >> 9) & 15, lane = (r >> 3) & 63, j = r & 7;
    const int n = nf * 16 + (lane & 15), k = ks * 32 + (lane >> 4) * 8 + j;
    const float* W = (sel == 0) ? Wq : ((sel == 1) ? Wk : Wv);
    Bqkv[idx] = (short)f2bf(W[k * 256 + n]);
  }
  for (int idx = t0; idx < 65536; idx += stride) {
    const int ks = idx >> 13, nf = (idx >> 9) & 15, lane = (idx >> 3) & 63, j = idx & 7;
    const int n = nf * 16 + (lane & 15), k = ks * 32 + (lane >> 4) * 8 + j;
    WoT[idx] = (short)f2bf(Wo[k * 256 + n]);
  }
  for (int idx = t0; idx < 9 * 65536; idx += stride) {
    const int off = idx >> 16, r = idx & 65535;
    const int ks = r >> 13, nf = (r >> 9) & 15, lane = (r >> 3) & 63, j = r & 7;
    const int oc = nf * 16 + (lane & 15), cin = ks * 32 + (lane >> 4) * 8 + j;
    Bconv[idx] = (short)f2bf(conv_w[(oc * 256 + cin) * 9 + off]);
  }
  for (int idx = t0; idx < 128 * 32; idx += stride) {
    const int row = idx >> 5, kk = idx & 31;
    const float v = (row < MFEAT) ? proj[row * 32 + kk] * NORMC : 0.f;
    projb[idx] = (short)f2bf(v);
  }
}

// per-channel sum / sumsq over (B,H,W) for NCHW fp32 x; grid = B*C blocks
__global__ void bn_stats_kernel(const float* __restrict__ src, float* __restrict__ sums) {
  const int c = blockIdx.x & 255, b = blockIdx.x >> 8;
  const float* p = src + ((size_t)b * CDIM + c) * SDIM;
  float s = 0.f, s2 = 0.f;
  for (int i = threadIdx.x; i < SDIM; i += 256) {
    const float v = p[i];
    s += v; s2 += v * v;
  }
  for (int o = 32; o > 0; o >>= 1) { s += __shfl_down(s, o); s2 += __shfl_down(s2, o); }
  __shared__ float ls[4], ls2[4];
  const int w = threadIdx.x >> 6;
  if ((threadIdx.x & 63) == 0) { ls[w] = s; ls2[w] = s2; }
  __syncthreads();
  if (threadIdx.x == 0) {
    s = ls[0] + ls[1] + ls[2] + ls[3];
    s2 = ls2[0] + ls2[1] + ls2[2] + ls2[3];
    atomicAdd(&sums[c], s);
    atomicAdd(&sums[256 + c], s2);
  }
}

__global__ void bn_final_kernel(const float* __restrict__ sums, const float* __restrict__ gamma,
                                const float* __restrict__ beta, float* __restrict__ scsh) {
  const int c = threadIdx.x;
  const float mean = sums[c] * (1.f / NPIX);
  const float var = sums[256 + c] * (1.f / NPIX) - mean * mean;
  const float sc = gamma[c] * rsqrtf(var + 1e-5f);
  scsh[c] = sc;
  scsh[256 + c] = beta[c] - mean * sc;
}

// ---------------------------------------------------------------------------
// x NCHW f32 -> dst NHWC bf16; mode=1 applies relu(bn1) using scsh.
__global__ void transpose_x(const float* __restrict__ x, const float* __restrict__ scsh,
                            short* __restrict__ dst, int mode) {
  __shared__ short T[64][72];
  const int t0 = blockIdx.x * 64;
  const int b = t0 / SDIM;
  const int s0 = t0 - b * SDIM;
  const int c0 = blockIdx.y * 64;
  const int tid = threadIdx.x;
  const int tokl = tid & 63, cl = tid >> 6;
  const float* xb = x + ((size_t)b * CDIM + c0) * SDIM + s0;
#pragma unroll
  for (int i = 0; i < 16; ++i) {
    const int c = i * 4 + cl;
    float v = xb[(size_t)c * SDIM + tokl];
    if (mode) v = fmaxf(v * scsh[c0 + c] + scsh[256 + c0 + c], 0.f);
    T[c][tokl] = (short)f2bf(v);
  }
  __syncthreads();
#pragma unroll
  for (int j = 0; j < 2; ++j) {
    const int idx = tid + j * 256;
    const int tk = idx >> 3, ch8 = idx & 7;
    unsigned short h[8];
#pragma unroll
    for (int jj = 0; jj < 8; ++jj) h[jj] = (unsigned short)T[ch8 * 8 + jj][tk];
    unsigned long long* p = (unsigned long long*)&dst[(size_t)(t0 + tk) * 256 + c0 + ch8 * 8];
    p[0] = pack4(h);
    p[1] = pack4(h + 4);
  }
}

// u2 = relu(bn2(z))  (NHWC bf16 elementwise)
__global__ void u2_kernel(const short* __restrict__ z, const float* __restrict__ scsh,
                          short* __restrict__ u2) {
  const int nchunks = NTOK * 32;
  for (int idx = blockIdx.x * blockDim.x + threadIdx.x; idx < nchunks;
       idx += gridDim.x * blockDim.x) {
    const int cch = idx & 31;
    const short8 v = *(const short8*)&z[(size_t)idx * 8];
    unsigned short h[8];
#pragma unroll
    for (int j = 0; j < 8; ++j) {
      const int c = cch * 8 + j;
      h[j] = f2bf(fmaxf(bf2f(v[j]) * scsh[c] + scsh[256 + c], 0.f));
    }
    unsigned long long* p = (unsigned long long*)&u2[(size_t)idx * 8];
    p[0] = pack4(h);
    p[1] = pack4(h + 4);
  }
}

// ---------------------------------------------------------------------------
// QKV GEMM: M=64, N=256 per block (grid 784 x 3, blockIdx.y = sel 0=q/1=k/2=v).
// A = u1 NHWC bf16; B = Bqkv fragment-major packed. Per wave: rf=4, cf=4.
// q/k epilogue: LDS transpose -> full 64B token rows (short8 stores).
// v epilogue: LDS transpose zt2[chn][tok] (pitch 66) -> 128B contiguous rows.
// All global row indices use batch-local s0 (= token0 - bb*SDIM).
__global__ __launch_bounds__(256, 4)
void qkv_gemm(const short* __restrict__ u1, const short* __restrict__ BT,
              const float* __restrict__ bq, const float* __restrict__ bk,
              const float* __restrict__ bv,
              short* __restrict__ qo, short* __restrict__ ko, short* __restrict__ vo) {
  __shared__ short A_s[64 * 264];  // staging pitch 256; epilogues reuse
  const int tid = threadIdx.x;
  const int mtile = blockIdx.x, sel = blockIdx.y;
  const int token0 = mtile * 64;
  {
    const int trow = tid >> 5, cch = tid & 31;
    const short* src = u1 + (size_t)token0 * 256;
#pragma unroll
    for (int i = 0; i < 8; ++i) {
      const int tok = trow + i * 8;
      const short8 vv = *(const short8*)&src[tok * 256 + cch * 8];
      const int phys = cch ^ (tok & 31);
      *(short8*)&A_s[tok * 256 + phys * 8] = vv;
    }
  }
  __syncthreads();

  const int lane = tid & 63, wv = tid >> 6;
  const int quad = lane >> 4, l15 = lane & 15;
  const f32x4 vzero = {0.f, 0.f, 0.f, 0.f};
  f32x4 acc[4][4];
#pragma unroll
  for (int i = 0; i < 4; ++i)
#pragma unroll
    for (int j = 0; j < 4; ++j) acc[i][j] = vzero;
  const short* Bp = BT + ((size_t)sel << 16);
#pragma unroll
  for (int ks = 0; ks < 8; ++ks) {
    short8 af[4], bfr[4];
#pragma unroll
    for (int rf = 0; rf < 4; ++rf) {
      const int row = rf * 16 + l15;
      const int phys = (ks * 4 + quad) ^ (row & 31);
      af[rf] = *(const short8*)&A_s[row * 256 + phys * 8];
    }
#pragma unroll
    for (int cf = 0; cf < 4; ++cf)
      bfr[cf] = *(const short8*)&Bp[((((ks << 4) | (wv << 2) | cf) << 6) | lane) << 3];
#pragma unroll
    for (int rf = 0; rf < 4; ++rf)
#pragma unroll
      for (int cf = 0; cf < 4; ++cf)
        acc[rf][cf] = mfma16(af[rf], bfr[cf], acc[rf][cf]);
  }

  const int bb = token0 / SDIM;
  const int s0 = token0 - bb * SDIM;  // batch-local token index (the fix)
  if (sel < 2) {
    // LDS transpose epilogue: acc -> zt[tok][chn] (bias fused), then
    // coalesced short8 writes of full [tok][dd] rows.
    __syncthreads();
    short* zt = A_s;
#pragma unroll
    for (int cf = 0; cf < 4; ++cf) {
      const int chn = wv * 64 + cf * 16 + l15;
      const float bias = (sel == 0) ? bq[chn] : bk[chn];
#pragma unroll
      for (int rf = 0; rf < 4; ++rf) {
        const int tl = rf * 16 + quad * 4;
#pragma unroll
        for (int r = 0; r < 4; ++r)
          zt[(tl + r) * 264 + chn] = (short)f2bf(acc[rf][cf][r] + bias);
      }
    }
    __syncthreads();
    short* dst = (sel == 0) ? qo : ko;
#pragma unroll
    for (int j = 0; j < 8; ++j) {
      const int idx = tid + j * 256;  // 0..2047
      const int tl = idx >> 5, ch = idx & 31;  // ch = chn-group of 8
      const int head = ch >> 2, dd0 = (ch & 3) * 8;
      const short8 vv = *(const short8*)&zt[tl * 264 + ch * 8];
      *(short8*)&dst[((size_t)(bb * NHEAD + head) * SDIM + s0 + tl) * DHEAD + dd0] = vv;
    }
  } else {
    // v epilogue: zt2[chn][tok], pitch 66 (256*66 = 64*264 exactly).
    __syncthreads();
    short* zt = A_s;
#pragma unroll
    for (int cf = 0; cf < 4; ++cf) {
      const int chn = wv * 64 + cf * 16 + l15;
      const float bias = bv[chn];
#pragma unroll
      for (int rf = 0; rf < 4; ++rf) {
        const int tl = rf * 16 + quad * 4;
#pragma unroll
        for (int r = 0; r < 4; ++r)
          zt[chn * 66 + tl + r] = (short)f2bf(acc[rf][cf][r] + bias);
      }
    }
    __syncthreads();
#pragma unroll
    for (int j = 0; j < 8; ++j) {
      const int idx = tid + j * 256;  // 0..2047
      const int chn = idx >> 3, tch = (idx & 7) * 8;
      const int head = chn >> 5, dd = chn & 31;
      const short8 vv = *(const short8*)&zt[chn * 66 + tch];
      *(short8*)&vo[((size_t)(bb * NHEAD + head) * DHEAD + dd) * SDIM + s0 + tch] = vv;
    }
  }
}

// ---------------------------------------------------------------------------
// Phase 1: per (b,h): phi_k = relu(k @ projb^T)+eps via MFMA (K=32),
// LDS round-trip [mf][tok], then ctx[mf][d] += phi_k^T @ v, ksum[mf] += sums.
// grid = 512: bh(128) x quarter(4); (quarter,wave) owns ch residues mod 16.
__global__ __launch_bounds__(256, 2)
void attn_phase1(const short* __restrict__ kk, const short* __restrict__ vt,
                 const short* __restrict__ projb, float* __restrict__ ctx_acc,
                 float* __restrict__ ksum) {
  __shared__ short proj_s[128 * 40];
  __shared__ short phi_s[4][128 * 40];
  const int tid = threadIdx.x;
  const int bh = blockIdx.x >> 2, qI = blockIdx.x & 3;
  for (int i = tid; i < 128 * 32; i += 256)
    proj_s[(i >> 5) * 40 + (i & 31)] = projb[i];
  __syncthreads();
  const int lane = tid & 63, wv = tid >> 6;
  const int quad = lane >> 4, l15 = lane & 15;
  const short* kb = kk + (size_t)bh * SDIM * DHEAD;
  const short* vb = vt + (size_t)bh * DHEAD * SDIM;
  short* myphi = phi_s[wv];
  const f32x4 vzero = {0.f, 0.f, 0.f, 0.f};
  f32x4 cacc[8][2];
  float ks_acc[8];
#pragma unroll
  for (int i = 0; i < 8; ++i) { cacc[i][0] = vzero; cacc[i][1] = vzero; ks_acc[i] = 0.f; }

  for (int ch = qI * 4 + wv; ch < 98; ch += 16) {
    const int tok0 = ch * 32;
    short8 afr[2];
    afr[0] = *(const short8*)&kb[(size_t)(tok0 + l15) * DHEAD + quad * 8];
    afr[1] = *(const short8*)&kb[(size_t)(tok0 + 16 + l15) * DHEAD + quad * 8];
#pragma unroll
    for (int cf = 0; cf < 8; ++cf) {
      const short8 bfr = *(const short8*)&proj_s[(cf * 16 + l15) * 40 + quad * 8];
      const float epsv = (cf < 6) ? 1e-3f : ((cf == 6) ? ((l15 < 14) ? 1e-3f : 0.f) : 0.f);
#pragma unroll
      for (int fr = 0; fr < 2; ++fr) {
        f32x4 p = mfma16(afr[fr], bfr, vzero);
        unsigned short h4[4];
        float srow = 0.f;
#pragma unroll
        for (int r = 0; r < 4; ++r) {
          const float pv = fmaxf(p[r], 0.f) + epsv;
          srow += pv;
          h4[r] = f2bf(pv);
        }
        ks_acc[cf] += srow;
        *(unsigned long long*)&myphi[(cf * 16 + l15) * 40 + fr * 16 + quad * 4] = pack4(h4);
      }
    }
    short8 bv2[2];
    bv2[0] = *(const short8*)&vb[(size_t)l15 * SDIM + tok0 + quad * 8];
    bv2[1] = *(const short8*)&vb[(size_t)(16 + l15) * SDIM + tok0 + quad * 8];
#pragma unroll
    for (int mfr = 0; mfr < 8; ++mfr) {
      const short8 a2 = *(const short8*)&myphi[(mfr * 16 + l15) * 40 + quad * 8];
      cacc[mfr][0] = mfma16(a2, bv2[0], cacc[mfr][0]);
      cacc[mfr][1] = mfma16(a2, bv2[1], cacc[mfr][1]);
    }
  }
#pragma unroll
  for (int cf = 0; cf < 8; ++cf) {
    float v = ks_acc[cf];
    v += __shfl_xor(v, 16);
    v += __shfl_xor(v, 32);
    if (lane < 16) atomicAdd(&ksum[bh * 128 + cf * 16 + lane], v);
  }
  float* cb = ctx_acc + (size_t)bh * 4096;
#pragma unroll
  for (int mfr = 0; mfr < 8; ++mfr)
#pragma unroll
    for (int df = 0; df < 2; ++df)
#pragma unroll
      for (int r = 0; r < 4; ++r)
        atomicAdd(&cb[(mfr * 16 + quad * 4 + r) * 32 + df * 16 + l15], cacc[mfr][df][r]);
}

// Phase 2: phi_q via MFMA, out = phi_q@ctx * 1/denom; writes Y NHWC bf16
// via per-wave LDS transpose. ctx_finalize fused into ctx_s staging.
// grid = 512: bh(128) x quarter(4).
__global__ __launch_bounds__(256, 2)
void attn_phase2(const short* __restrict__ qq, const float* __restrict__ ctx_acc,
                 const float* __restrict__ ksum, const short* __restrict__ projb,
                 short* __restrict__ Yn) {
  __shared__ short proj_s[128 * 40];
  __shared__ short ctx_s[48 * 136];
  __shared__ short phi_s[4][32 * 136];
  const int tid = threadIdx.x;
  const int bh = blockIdx.x >> 2, qI = blockIdx.x & 3;
  for (int i = tid; i < 128 * 32; i += 256)
    proj_s[(i >> 5) * 40 + (i & 31)] = projb[i];
  {
    const float* ca = ctx_acc + (size_t)bh * 4096;
    const float* ks = ksum + bh * 128;
    for (int i = tid; i < 48 * 128; i += 256) {
      const int row = i >> 7, mf = i & 127;
      const float v = (row < 32) ? ca[mf * 32 + row] : ((row == 32) ? ks[mf] : 0.f);
      ctx_s[row * 136 + mf] = (short)f2bf(v);
    }
  }
  __syncthreads();
  const int lane = tid & 63, wv = tid >> 6;
  const int quad = lane >> 4, l15 = lane & 15;
  const int b = bh >> 3, head = bh & 7;
  const short* qb = qq + (size_t)bh * SDIM * DHEAD;
  short* myphi = phi_s[wv];
  const f32x4 vzero = {0.f, 0.f, 0.f, 0.f};

  for (int ch = qI * 4 + wv; ch < 98; ch += 16) {
    const int tok0 = ch * 32;
    short8 afr[2];
    afr[0] = *(const short8*)&qb[(size_t)(tok0 + l15) * DHEAD + quad * 8];
    afr[1] = *(const short8*)&qb[(size_t)(tok0 + 16 + l15) * DHEAD + quad * 8];
#pragma unroll
    for (int cf = 0; cf < 8; ++cf) {
      const short8 bfr = *(const short8*)&proj_s[(cf * 16 + l15) * 40 + quad * 8];
      const float epsv = (cf < 6) ? 1e-3f : ((cf == 6) ? ((l15 < 14) ? 1e-3f : 0.f) : 0.f);
#pragma unroll
      for (int fr = 0; fr < 2; ++fr) {
        f32x4 p = mfma16(afr[fr], bfr, vzero);
#pragma unroll
        for (int r = 0; r < 4; ++r) {
          const float pv = fmaxf(p[r], 0.f) + epsv;
          myphi[(fr * 16 + quad * 4 + r) * 136 + cf * 16 + l15] = (short)f2bf(pv);
        }
      }
    }
    f32x4 oacc[2][3];
#pragma unroll
    for (int fr = 0; fr < 2; ++fr)
#pragma unroll
      for (int c3 = 0; c3 < 3; ++c3) oacc[fr][c3] = vzero;
#pragma unroll
    for (int ksI = 0; ksI < 4; ++ksI) {
      short8 a3[2];
      a3[0] = *(const short8*)&myphi[l15 * 136 + ksI * 32 + quad * 8];
      a3[1] = *(const short8*)&myphi[(16 + l15) * 136 + ksI * 32 + quad * 8];
#pragma unroll
      for (int c3 = 0; c3 < 3; ++c3) {
        const short8 b3 = *(const short8*)&ctx_s[(c3 * 16 + l15) * 136 + ksI * 32 + quad * 8];
        oacc[0][c3] = mfma16(a3[0], b3, oacc[0][c3]);
        oacc[1][c3] = mfma16(a3[1], b3, oacc[1][c3]);
      }
    }
#pragma unroll
    for (int fr = 0; fr < 2; ++fr) {
      float dinv[4];
#pragma unroll
      for (int r = 0; r < 4; ++r) {
        const float den = __shfl(oacc[fr][2][r], quad << 4);
        dinv[r] = 1.f / den;
      }
#pragma unroll
      for (int c3 = 0; c3 < 2; ++c3)
#pragma unroll
        for (int r = 0; r < 4; ++r)
          myphi[(fr * 16 + quad * 4 + r) * 40 + c3 * 16 + l15] =
              (short)f2bf(oacc[fr][c3][r] * dinv[r]);
    }
    const size_t trow0 = (size_t)(b * SDIM + tok0) * 256 + head * 32;
#pragma unroll
    for (int it = 0; it < 2; ++it) {
      const int idx = it * 64 + lane;
      const int tl = idx >> 2, c4 = idx & 3;
      const short8 vv = *(const short8*)&myphi[tl * 40 + c4 * 8];
      *(short8*)&Yn[trow0 + (size_t)tl * 256 + c4 * 8] = vv;
    }
  }
}

// ---------------------------------------------------------------------------
// Wo GEMM: M=64, N=256 (grid 784). A = Y NHWC bf16, B = WoT packed.
// z = Y@Wo + bo + xh (bf16 NHWC) via LDS transpose epilogue; bn2 stats fused.
__global__ __launch_bounds__(256, 4)
void wo_gemm(const short* __restrict__ Yn, const short* __restrict__ WoT,
             const float* __restrict__ bo, const short* __restrict__ xh,
             short* __restrict__ z, float* __restrict__ sums) {
  __shared__ short A_s[64 * 264];  // staging pitch 256; epilogue zt pitch 264
  const int tid = threadIdx.x;
  const int mtile = blockIdx.x;
  const int token0 = mtile * 64;
  {
    const int trow = tid >> 5, cch = tid & 31;
    const short* src = Yn + (size_t)token0 * 256;
#pragma unroll
    for (int i = 0; i < 8; ++i) {
      const int tok = trow + i * 8;
      const short8 vv = *(const short8*)&src[tok * 256 + cch * 8];
      const int phys = cch ^ (tok & 31);
      *(short8*)&A_s[tok * 256 + phys * 8] = vv;
    }
  }
  __syncthreads();

  const int lane = tid & 63, wv = tid >> 6;
  const int quad = lane >> 4, l15 = lane & 15;
  const f32x4 vzero = {0.f, 0.f, 0.f, 0.f};
  f32x4 acc[4][4];
#pragma unroll
  for (int i = 0; i < 4; ++i)
#pragma unroll
    for (int j = 0; j < 4; ++j) acc[i][j] = vzero;
#pragma unroll
  for (int ks = 0; ks < 8; ++ks) {
    short8 af[4], bfr[4];
#pragma unroll
    for (int rf = 0; rf < 4; ++rf) {
      const int row = rf * 16 + l15;
      const int phys = (ks * 4 + quad) ^ (row & 31);
      af[rf] = *(const short8*)&A_s[row * 256 + phys * 8];
    }
#pragma unroll
    for (int cf = 0; cf < 4; ++cf)
      bfr[cf] = *(const short8*)&WoT[((((ks << 4) | (wv << 2) | cf) << 6) | lane) << 3];
#pragma unroll
    for (int rf = 0; rf < 4; ++rf)
#pragma unroll
      for (int cf = 0; cf < 4; ++cf)
        acc[rf][cf] = mfma16(af[rf], bfr[cf], acc[rf][cf]);
  }
  // epilogue: C-frag -> LDS [tok][oc] (bias fused), then coalesced NHWC rows
  // (+xh) with fused bn2 stats.
  __syncthreads();
  short* zt = A_s;
#pragma unroll
  for (int cf = 0; cf < 4; ++cf) {
    const int ocl = wv * 64 + cf * 16 + l15;
    const float bias = bo[ocl];
#pragma unroll
    for (int rf = 0; rf < 4; ++rf) {
      const int tl = rf * 16 + quad * 4;
#pragma unroll
      for (int r = 0; r < 4; ++r)
        zt[(tl + r) * 264 + ocl] = (short)f2bf(acc[rf][cf][r] + bias);
    }
  }
  __syncthreads();
  float s[8], s2[8];
#pragma unroll
  for (int j = 0; j < 8; ++j) { s[j] = 0.f; s2[j] = 0.f; }
#pragma unroll
  for (int j = 0; j < 8; ++j) {
    const int idx = tid + j * 256;  // 0..2047
    const int tl = idx >> 5, ch = idx & 31;  // ch == tid & 31 (fixed per thread)
    const short8 zv = *(const short8*)&zt[tl * 264 + ch * 8];
    const size_t gbase = (size_t)(token0 + tl) * 256 + ch * 8;
    const short8 xv = *(const short8*)&xh[gbase];
    unsigned short h[8];
#pragma unroll
    for (int jj = 0; jj < 8; ++jj) {
      h[jj] = f2bf(bf2f(zv[jj]) + bf2f(xv[jj]));
      const float f = bf2f((short)h[jj]);
      s[jj] += f; s2[jj] += f * f;
    }
    unsigned long long* p = (unsigned long long*)&z[gbase];
    p[0] = pack4(h);
    p[1] = pack4(h + 4);
  }
  // bn2 stats reduction (identical structure to old bn_stats_nhwc)
  __syncthreads();
  float* L = (float*)A_s;  // 256 x 16 floats = 16KB
#pragma unroll
  for (int j = 0; j < 8; ++j) { L[tid * 16 + j] = s[j]; L[tid * 16 + 8 + j] = s2[j]; }
  __syncthreads();
  const int c = tid, cgi = c >> 3, j2 = c & 7;
  float a = 0.f, b2 = 0.f;
#pragma unroll
  for (int tr = 0; tr < 8; ++tr) {
    a += L[(tr * 32 + cgi) * 16 + j2];
    b2 += L[(tr * 32 + cgi) * 16 + 8 + j2];
  }
  atomicAdd(&sums[c], a);
  atomicAdd(&sums[256 + c], b2);
}

// ---------------------------------------------------------------------------
// Conv 3x3 implicit GEMM (round-1 proven shape): M=32, N=256, grid 1568.
// Per dy band: stage 34(+6 pad) halo tokens once; dx taps = shifted LDS reads
// with per-lane boundary masks. Register prefetch of next dy overlaps compute.
__global__ __launch_bounds__(256, 4)
void conv_gemm(const short* __restrict__ u2, const short* __restrict__ Bc,
               const float* __restrict__ x, float* __restrict__ out) {
  __shared__ short A_s[40 * 256];  // 20.5 KB
  const int tid = threadIdx.x;
  // XCD-aware bijective swizzle: 1568 = 8 * 196.
  const int bid = blockIdx.x;
  const int mtile = (bid & 7) * 196 + (bid >> 3);
  const int bb = mtile / 98, s0 = (mtile - bb * 98) * 32;
  const short* ub = u2 + (size_t)bb * SDIM * 256;
  const int lane = tid & 63, wv = tid >> 6;
  const int quad = lane >> 4, l15 = lane & 15;
  const f32x4 vzero = {0.f, 0.f, 0.f, 0.f};
  const short8 szero = {0, 0, 0, 0, 0, 0, 0, 0};
  f32x4 acc[2][4];
#pragma unroll
  for (int i = 0; i < 2; ++i)
#pragma unroll
    for (int j = 0; j < 4; ++j) acc[i][j] = vzero;

  int vy[2], vx[2];
#pragma unroll
  for (int rf = 0; rf < 2; ++rf) {
    const int so = s0 + rf * 16 + l15;
    vy[rf] = so / 56;
    vx[rf] = so - vy[rf] * 56;
  }

  short8 pref[5];
#define LOAD_DY(DYI)                                                           \
  {                                                                            \
    const int srow0 = s0 + ((DYI)-1) * 56 - 1;                                 \
    _Pragma("unroll") for (int it = 0; it < 5; ++it) {                         \
      const int chunk = tid + it * 256;                                        \
      const int idx = chunk >> 5, cchl = chunk & 31;                           \
      const int s = srow0 + idx;                                               \
      short8 vv = {0, 0, 0, 0, 0, 0, 0, 0};                                    \
      if ((unsigned)s < (unsigned)SDIM)                                        \
        vv = *(const short8*)&ub[(size_t)s * 256 + cchl * 8];                  \
      pref[it] = vv;                                                           \
    }                                                                          \
  }

  LOAD_DY(0);
#pragma unroll
  for (int dyi = 0; dyi < 3; ++dyi) {
    if (dyi) __syncthreads();
#pragma unroll
    for (int it = 0; it < 5; ++it) {
      const int chunk = tid + it * 256;
      const int idx = chunk >> 5, cchl = chunk & 31;
      const int phys = cchl ^ (idx & 31);
      *(short8*)&A_s[idx * 256 + phys * 8] = pref[it];
    }
    __syncthreads();
    if (dyi < 2) LOAD_DY(dyi + 1);  // overlap next dy staging with compute
#pragma unroll
    for (int dxi = 0; dxi < 3; ++dxi) {
      const short* Bp = Bc + ((dyi * 3 + dxi) << 16);
      bool vmask[2];
#pragma unroll
      for (int rf = 0; rf < 2; ++rf)
        vmask[rf] = ((unsigned)(vy[rf] + dyi - 1) < 56u) &&
                    ((unsigned)(vx[rf] + dxi - 1) < 56u);
#pragma unroll
      for (int ks = 0; ks < 8; ++ks) {
        short8 af[2], bfr[4];
#pragma unroll
        for (int rf = 0; rf < 2; ++rf) {
          const int row = rf * 16 + l15 + dxi;  // shifted read = dx tap
          const int phys = (ks * 4 + quad) ^ (row & 31);
          const short8 a = *(const short8*)&A_s[row * 256 + phys * 8];
          af[rf] = vmask[rf] ? a : szero;
        }
#pragma unroll
        for (int cf = 0; cf < 4; ++cf)
          bfr[cf] = *(const short8*)&Bp[((((ks << 4) | (wv << 2) | cf) << 6) | lane) << 3];
#pragma unroll
        for (int rf = 0; rf < 2; ++rf)
#pragma unroll
          for (int cf = 0; cf < 4; ++cf)
            acc[rf][cf] = mfma16(af[rf], bfr[cf], acc[rf][cf]);
      }
    }
  }
#undef LOAD_DY

#pragma unroll
  for (int cf = 0; cf < 4; ++cf) {
    const int oc = wv * 64 + cf * 16 + l15;
#pragma unroll
    for (int rf = 0; rf < 2; ++rf) {
      const int ss = s0 + rf * 16 + quad * 4;
      const size_t base = ((size_t)(bb * CDIM + oc)) * SDIM + ss;
      const f32x4 xv = *(const f32x4*)(x + base);
      f32x4 res;
#pragma unroll
      for (int r = 0; r < 4; ++r) res[r] = acc[rf][cf][r] + xv[r];
      *(f32x4*)(out + base) = res;
    }
  }
}

// ---------------------------------------------------------------------------
extern "C" void kernel_launch(void* const* d_in, const int* in_sizes, int n_in,
                              void* d_out, int out_size, void* d_ws, size_t ws_size,
                              hipStream_t stream) {
  const float* x      = (const float*)d_in[0];
  const float* bn1_g  = (const float*)d_in[1];
  const float* bn1_b  = (const float*)d_in[2];
  const float* bn2_g  = (const float*)d_in[3];
  const float* bn2_b  = (const float*)d_in[4];
  const float* Wq     = (const float*)d_in[5];
  const float* bq     = (const float*)d_in[6];
  const float* Wk     = (const float*)d_in[7];
  const float* bk     = (const float*)d_in[8];
  const float* Wv     = (const float*)d_in[9];
  const float* bv     = (const float*)d_in[10];
  const float* Wo     = (const float*)d_in[11];
  const float* bo     = (const float*)d_in[12];
  const float* proj   = (const float*)d_in[13];
  const float* conv_w = (const float*)d_in[14];
  float* out = (float*)d_out;
  char* ws = (char*)d_ws;

  // ---- workspace layout ----
  const size_t OFF_K     = 0;           // bf16 k; then Y NHWC; then u2
  const size_t OFF_V     = 25690112;    // bf16 vT; then z NHWC
  const size_t OFF_BQKV  = 51380224;    // 393,216 B (packed)
  const size_t OFF_WOT   = 51773440;    // 131,072 B (packed)
  const size_t OFF_BCONV = 51904512;    // 1,179,648 B (packed)
  const size_t OFF_PROJB = 53084160;    // 8,192 B
  const size_t OFF_CTXA  = 53092352;    // 2,097,152 B
  const size_t OFF_KSUM  = 55189504;    // 65,536 B
  const size_t OFF_BN1S  = 55255040;    // 2,048 B
  const size_t OFF_BN2S  = 55257088;    // 2,048 B
  const size_t OFF_SC1   = 55259136;    // 2,048 B
  const size_t OFF_SC2   = 55261184;    // 2,048 B
  const size_t WS_NEEDED = 56836096;

  if (ws_size < WS_NEEDED) {
    zero_kernel<<<2048, 256, 0, stream>>>(out, out_size);
    return;
  }

  // d_out doubles as scratch: [q (25.7MB) | u1 then xh (25.7MB)]
  short* qb    = (short*)d_out;
  short* half2 = (short*)d_out + 12845056;
  short* kb    = (short*)(ws + OFF_K);
  short* vtb   = (short*)(ws + OFF_V);
  short* Yn    = (short*)(ws + OFF_K);
  short* zbuf  = (short*)(ws + OFF_V);
  short* u2b   = (short*)(ws + OFF_K);
  short* Bqkv  = (short*)(ws + OFF_BQKV);
  short* WoT   = (short*)(ws + OFF_WOT);
  short* Bconv = (short*)(ws + OFF_BCONV);
  short* projb = (short*)(ws + OFF_PROJB);
  float* ctxa  = (float*)(ws + OFF_CTXA);
  float* ksum  = (float*)(ws + OFF_KSUM);
  float* bn1s  = (float*)(ws + OFF_BN1S);
  float* bn2s  = (float*)(ws + OFF_BN2S);
  float* sc1   = (float*)(ws + OFF_SC1);
  float* sc2   = (float*)(ws + OFF_SC2);

  zero_kernel<<<512, 256, 0, stream>>>(ctxa, (2097152 + 65536 + 2048 + 2048) / 4);
  prep_kernel<<<256, 256, 0, stream>>>(Wq, Wk, Wv, Wo, proj, conv_w, Bqkv, WoT, Bconv, projb);
  bn_stats_kernel<<<4096, 256, 0, stream>>>(x, bn1s);
  bn_final_kernel<<<1, 256, 0, stream>>>(bn1s, bn1_g, bn1_b, sc1);
  transpose_x<<<dim3(784, 4), 256, 0, stream>>>(x, sc1, half2, 1);
  qkv_gemm<<<dim3(784, 3), 256, 0, stream>>>(half2, Bqkv, bq, bk, bv, qb, kb, vtb);
  attn_phase1<<<512, 256, 0, stream>>>(kb, vtb, projb, ctxa, ksum);
  attn_phase2<<<512, 256, 0, stream>>>(qb, ctxa, ksum, projb, Yn);
  transpose_x<<<dim3(784, 4), 256, 0, stream>>>(x, sc1, half2, 0);
  wo_gemm<<<784, 256, 0, stream>>>(Yn, WoT, bo, half2, zbuf, bn2s);
  bn_final_kernel<<<1, 256, 0, stream>>>(bn2s, bn2_g, bn2_b, sc2);
  u2_kernel<<<1024, 256, 0, stream>>>(zbuf, sc2, u2b);
  conv_gemm<<<1568, 256, 0, stream>>>(u2b, Bconv, x, out);
}

// Round 11
// 459.962 us; speedup vs baseline: 1.0899x; 1.0899x over previous
//
#include <hip/hip_runtime.h>

// ---------------------------------------------------------------------------
// ACBlock: BN1+ReLU -> Performer attention -> +x -> BN2+ReLU -> conv3x3 -> +x
// B=16 C=256 H=W=56  S=3136 tokens/batch, NTOK=50176, heads=8, d=32, m=110
// Round 16 (from corrected 501.3us): delete second transpose_x. wo_gemm adds
// the residual DIRECTLY from f32 NCHW x in its zt-write stage (proven correct
// in round 12; now isolated). Net -51.4MB HBM + one launch. Everything else
// identical to round-15 (batch-offset-fixed) kernel.
// ---------------------------------------------------------------------------

typedef short short8 __attribute__((ext_vector_type(8)));
typedef float f32x4 __attribute__((ext_vector_type(4)));

#define DEVI static __device__ __forceinline__

#define CDIM 256
#define SDIM 3136
#define NTOK 50176
#define NHEAD 8
#define DHEAD 32
#define MFEAT 110
#define NORMC 0.42044820762685725f  // 32^-0.25
#define NPIX 50176.0f

DEVI unsigned short f2bf(float f) {
  union { float f; unsigned u; } v; v.f = f;
  unsigned r = v.u + 0x7fffu + ((v.u >> 16) & 1u);
  return (unsigned short)(r >> 16);
}

DEVI float bf2f(short h) {
  union { unsigned u; float f; } v;
  v.u = ((unsigned)(unsigned short)h) << 16;
  return v.f;
}

DEVI f32x4 mfma16(short8 a, short8 b, f32x4 c) {
  return __builtin_amdgcn_mfma_f32_16x16x32_bf16(a, b, c, 0, 0, 0);
}

DEVI unsigned long long pack4(const unsigned short* h) {
  return (unsigned long long)(h[0] | ((unsigned)h[1] << 16)) |
         ((unsigned long long)(h[2] | ((unsigned)h[3] << 16)) << 32);
}

// ---------------------------------------------------------------------------
__global__ void zero_kernel(float* p, int n) {
  for (int i = blockIdx.x * blockDim.x + threadIdx.x; i < n; i += gridDim.x * blockDim.x)
    p[i] = 0.f;
}

// Fragment-major packed B operands.
// Layout: packed[(ks*16 + nf)*512 + lane*8 + j] = B[n = nf*16 + (lane&15)]
//                                                  [k = ks*32 + (lane>>4)*8 + j]
__global__ void prep_kernel(const float* __restrict__ Wq, const float* __restrict__ Wk,
                            const float* __restrict__ Wv, const float* __restrict__ Wo,
                            const float* __restrict__ proj, const float* __restrict__ conv_w,
                            short* __restrict__ Bqkv, short* __restrict__ WoT,
                            short* __restrict__ Bconv, short* __restrict__ projb) {
  const int t0 = blockIdx.x * blockDim.x + threadIdx.x;
  const int stride = gridDim.x * blockDim.x;
  for (int idx = t0; idx < 3 * 65536; idx += stride) {
    const int sel = idx >> 16, r = idx & 65535;
    const int ks = r >> 13, nf = (r >> 9) & 15, lane = (r >> 3) & 63, j = r & 7;
    const int n = nf * 16 + (lane & 15), k = ks * 32 + (lane >> 4) * 8 + j;
    const float* W = (sel == 0) ? Wq : ((sel == 1) ? Wk : Wv);
    Bqkv[idx] = (short)f2bf(W[k * 256 + n]);
  }
  for (int idx = t0; idx < 65536; idx += stride) {
    const int ks = idx >> 13, nf = (idx >> 9) & 15, lane = (idx >> 3) & 63, j = idx & 7;
    const int n = nf * 16 + (lane & 15), k = ks * 32 + (lane >> 4) * 8 + j;
    WoT[idx] = (short)f2bf(Wo[k * 256 + n]);
  }
  for (int idx = t0; idx < 9 * 65536; idx += stride) {
    const int off = idx >> 16, r = idx & 65535;
    const int ks = r >> 13, nf = (r >> 9) & 15, lane = (r >> 3) & 63, j = r & 7;
    const int oc = nf * 16 + (lane & 15), cin = ks * 32 + (lane >> 4) * 8 + j;
    Bconv[idx] = (short)f2bf(conv_w[(oc * 256 + cin) * 9 + off]);
  }
  for (int idx = t0; idx < 128 * 32; idx += stride) {
    const int row = idx >> 5, kk = idx & 31;
    const float v = (row < MFEAT) ? proj[row * 32 + kk] * NORMC : 0.f;
    projb[idx] = (short)f2bf(v);
  }
}

// per-channel sum / sumsq over (B,H,W) for NCHW fp32 x; grid = B*C blocks
__global__ void bn_stats_kernel(const float* __restrict__ src, float* __restrict__ sums) {
  const int c = blockIdx.x & 255, b = blockIdx.x >> 8;
  const float* p = src + ((size_t)b * CDIM + c) * SDIM;
  float s = 0.f, s2 = 0.f;
  for (int i = threadIdx.x; i < SDIM; i += 256) {
    const float v = p[i];
    s += v; s2 += v * v;
  }
  for (int o = 32; o > 0; o >>= 1) { s += __shfl_down(s, o); s2 += __shfl_down(s2, o); }
  __shared__ float ls[4], ls2[4];
  const int w = threadIdx.x >> 6;
  if ((threadIdx.x & 63) == 0) { ls[w] = s; ls2[w] = s2; }
  __syncthreads();
  if (threadIdx.x == 0) {
    s = ls[0] + ls[1] + ls[2] + ls[3];
    s2 = ls2[0] + ls2[1] + ls2[2] + ls2[3];
    atomicAdd(&sums[c], s);
    atomicAdd(&sums[256 + c], s2);
  }
}

__global__ void bn_final_kernel(const float* __restrict__ sums, const float* __restrict__ gamma,
                                const float* __restrict__ beta, float* __restrict__ scsh) {
  const int c = threadIdx.x;
  const float mean = sums[c] * (1.f / NPIX);
  const float var = sums[256 + c] * (1.f / NPIX) - mean * mean;
  const float sc = gamma[c] * rsqrtf(var + 1e-5f);
  scsh[c] = sc;
  scsh[256 + c] = beta[c] - mean * sc;
}

// ---------------------------------------------------------------------------
// x NCHW f32 -> dst NHWC bf16 with relu(bn1) applied.
__global__ void transpose_x(const float* __restrict__ x, const float* __restrict__ scsh,
                            short* __restrict__ dst) {
  __shared__ short T[64][72];
  const int t0 = blockIdx.x * 64;
  const int b = t0 / SDIM;
  const int s0 = t0 - b * SDIM;
  const int c0 = blockIdx.y * 64;
  const int tid = threadIdx.x;
  const int tokl = tid & 63, cl = tid >> 6;
  const float* xb = x + ((size_t)b * CDIM + c0) * SDIM + s0;
#pragma unroll
  for (int i = 0; i < 16; ++i) {
    const int c = i * 4 + cl;
    float v = xb[(size_t)c * SDIM + tokl];
    v = fmaxf(v * scsh[c0 + c] + scsh[256 + c0 + c], 0.f);
    T[c][tokl] = (short)f2bf(v);
  }
  __syncthreads();
#pragma unroll
  for (int j = 0; j < 2; ++j) {
    const int idx = tid + j * 256;
    const int tk = idx >> 3, ch8 = idx & 7;
    unsigned short h[8];
#pragma unroll
    for (int jj = 0; jj < 8; ++jj) h[jj] = (unsigned short)T[ch8 * 8 + jj][tk];
    unsigned long long* p = (unsigned long long*)&dst[(size_t)(t0 + tk) * 256 + c0 + ch8 * 8];
    p[0] = pack4(h);
    p[1] = pack4(h + 4);
  }
}

// u2 = relu(bn2(z))  (NHWC bf16 elementwise)
__global__ void u2_kernel(const short* __restrict__ z, const float* __restrict__ scsh,
                          short* __restrict__ u2) {
  const int nchunks = NTOK * 32;
  for (int idx = blockIdx.x * blockDim.x + threadIdx.x; idx < nchunks;
       idx += gridDim.x * blockDim.x) {
    const int cch = idx & 31;
    const short8 v = *(const short8*)&z[(size_t)idx * 8];
    unsigned short h[8];
#pragma unroll
    for (int j = 0; j < 8; ++j) {
      const int c = cch * 8 + j;
      h[j] = f2bf(fmaxf(bf2f(v[j]) * scsh[c] + scsh[256 + c], 0.f));
    }
    unsigned long long* p = (unsigned long long*)&u2[(size_t)idx * 8];
    p[0] = pack4(h);
    p[1] = pack4(h + 4);
  }
}

// ---------------------------------------------------------------------------
// QKV GEMM: M=64, N=256 per block (grid 784 x 3, blockIdx.y = sel 0=q/1=k/2=v).
// A = u1 NHWC bf16; B = Bqkv fragment-major packed. Per wave: rf=4, cf=4.
// q/k epilogue: LDS transpose -> full 64B token rows (short8 stores).
// v epilogue: LDS transpose zt2[chn][tok] (pitch 66) -> 128B contiguous rows.
// All global row indices use batch-local s0 (= token0 - bb*SDIM).
__global__ __launch_bounds__(256, 4)
void qkv_gemm(const short* __restrict__ u1, const short* __restrict__ BT,
              const float* __restrict__ bq, const float* __restrict__ bk,
              const float* __restrict__ bv,
              short* __restrict__ qo, short* __restrict__ ko, short* __restrict__ vo) {
  __shared__ short A_s[64 * 264];  // staging pitch 256; epilogues reuse
  const int tid = threadIdx.x;
  const int mtile = blockIdx.x, sel = blockIdx.y;
  const int token0 = mtile * 64;
  {
    const int trow = tid >> 5, cch = tid & 31;
    const short* src = u1 + (size_t)token0 * 256;
#pragma unroll
    for (int i = 0; i < 8; ++i) {
      const int tok = trow + i * 8;
      const short8 vv = *(const short8*)&src[tok * 256 + cch * 8];
      const int phys = cch ^ (tok & 31);
      *(short8*)&A_s[tok * 256 + phys * 8] = vv;
    }
  }
  __syncthreads();

  const int lane = tid & 63, wv = tid >> 6;
  const int quad = lane >> 4, l15 = lane & 15;
  const f32x4 vzero = {0.f, 0.f, 0.f, 0.f};
  f32x4 acc[4][4];
#pragma unroll
  for (int i = 0; i < 4; ++i)
#pragma unroll
    for (int j = 0; j < 4; ++j) acc[i][j] = vzero;
  const short* Bp = BT + ((size_t)sel << 16);
#pragma unroll
  for (int ks = 0; ks < 8; ++ks) {
    short8 af[4], bfr[4];
#pragma unroll
    for (int rf = 0; rf < 4; ++rf) {
      const int row = rf * 16 + l15;
      const int phys = (ks * 4 + quad) ^ (row & 31);
      af[rf] = *(const short8*)&A_s[row * 256 + phys * 8];
    }
#pragma unroll
    for (int cf = 0; cf < 4; ++cf)
      bfr[cf] = *(const short8*)&Bp[((((ks << 4) | (wv << 2) | cf) << 6) | lane) << 3];
#pragma unroll
    for (int rf = 0; rf < 4; ++rf)
#pragma unroll
      for (int cf = 0; cf < 4; ++cf)
        acc[rf][cf] = mfma16(af[rf], bfr[cf], acc[rf][cf]);
  }

  const int bb = token0 / SDIM;
  const int s0 = token0 - bb * SDIM;  // batch-local token index
  if (sel < 2) {
    // LDS transpose epilogue: acc -> zt[tok][chn] (bias fused), then
    // coalesced short8 writes of full [tok][dd] rows.
    __syncthreads();
    short* zt = A_s;
#pragma unroll
    for (int cf = 0; cf < 4; ++cf) {
      const int chn = wv * 64 + cf * 16 + l15;
      const float bias = (sel == 0) ? bq[chn] : bk[chn];
#pragma unroll
      for (int rf = 0; rf < 4; ++rf) {
        const int tl = rf * 16 + quad * 4;
#pragma unroll
        for (int r = 0; r < 4; ++r)
          zt[(tl + r) * 264 + chn] = (short)f2bf(acc[rf][cf][r] + bias);
      }
    }
    __syncthreads();
    short* dst = (sel == 0) ? qo : ko;
#pragma unroll
    for (int j = 0; j < 8; ++j) {
      const int idx = tid + j * 256;  // 0..2047
      const int tl = idx >> 5, ch = idx & 31;  // ch = chn-group of 8
      const int head = ch >> 2, dd0 = (ch & 3) * 8;
      const short8 vv = *(const short8*)&zt[tl * 264 + ch * 8];
      *(short8*)&dst[((size_t)(bb * NHEAD + head) * SDIM + s0 + tl) * DHEAD + dd0] = vv;
    }
  } else {
    // v epilogue: zt2[chn][tok], pitch 66 (256*66 = 64*264 exactly).
    __syncthreads();
    short* zt = A_s;
#pragma unroll
    for (int cf = 0; cf < 4; ++cf) {
      const int chn = wv * 64 + cf * 16 + l15;
      const float bias = bv[chn];
#pragma unroll
      for (int rf = 0; rf < 4; ++rf) {
        const int tl = rf * 16 + quad * 4;
#pragma unroll
        for (int r = 0; r < 4; ++r)
          zt[chn * 66 + tl + r] = (short)f2bf(acc[rf][cf][r] + bias);
      }
    }
    __syncthreads();
#pragma unroll
    for (int j = 0; j < 8; ++j) {
      const int idx = tid + j * 256;  // 0..2047
      const int chn = idx >> 3, tch = (idx & 7) * 8;
      const int head = chn >> 5, dd = chn & 31;
      const short8 vv = *(const short8*)&zt[chn * 66 + tch];
      *(short8*)&vo[((size_t)(bb * NHEAD + head) * DHEAD + dd) * SDIM + s0 + tch] = vv;
    }
  }
}

// ---------------------------------------------------------------------------
// Phase 1: per (b,h): phi_k = relu(k @ projb^T)+eps via MFMA (K=32),
// LDS round-trip [mf][tok], then ctx[mf][d] += phi_k^T @ v, ksum[mf] += sums.
// grid = 512: bh(128) x quarter(4); (quarter,wave) owns ch residues mod 16.
__global__ __launch_bounds__(256, 2)
void attn_phase1(const short* __restrict__ kk, const short* __restrict__ vt,
                 const short* __restrict__ projb, float* __restrict__ ctx_acc,
                 float* __restrict__ ksum) {
  __shared__ short proj_s[128 * 40];
  __shared__ short phi_s[4][128 * 40];
  const int tid = threadIdx.x;
  const int bh = blockIdx.x >> 2, qI = blockIdx.x & 3;
  for (int i = tid; i < 128 * 32; i += 256)
    proj_s[(i >> 5) * 40 + (i & 31)] = projb[i];
  __syncthreads();
  const int lane = tid & 63, wv = tid >> 6;
  const int quad = lane >> 4, l15 = lane & 15;
  const short* kb = kk + (size_t)bh * SDIM * DHEAD;
  const short* vb = vt + (size_t)bh * DHEAD * SDIM;
  short* myphi = phi_s[wv];
  const f32x4 vzero = {0.f, 0.f, 0.f, 0.f};
  f32x4 cacc[8][2];
  float ks_acc[8];
#pragma unroll
  for (int i = 0; i < 8; ++i) { cacc[i][0] = vzero; cacc[i][1] = vzero; ks_acc[i] = 0.f; }

  for (int ch = qI * 4 + wv; ch < 98; ch += 16) {
    const int tok0 = ch * 32;
    short8 afr[2];
    afr[0] = *(const short8*)&kb[(size_t)(tok0 + l15) * DHEAD + quad * 8];
    afr[1] = *(const short8*)&kb[(size_t)(tok0 + 16 + l15) * DHEAD + quad * 8];
#pragma unroll
    for (int cf = 0; cf < 8; ++cf) {
      const short8 bfr = *(const short8*)&proj_s[(cf * 16 + l15) * 40 + quad * 8];
      const float epsv = (cf < 6) ? 1e-3f : ((cf == 6) ? ((l15 < 14) ? 1e-3f : 0.f) : 0.f);
#pragma unroll
      for (int fr = 0; fr < 2; ++fr) {
        f32x4 p = mfma16(afr[fr], bfr, vzero);
        unsigned short h4[4];
        float srow = 0.f;
#pragma unroll
        for (int r = 0; r < 4; ++r) {
          const float pv = fmaxf(p[r], 0.f) + epsv;
          srow += pv;
          h4[r] = f2bf(pv);
        }
        ks_acc[cf] += srow;
        *(unsigned long long*)&myphi[(cf * 16 + l15) * 40 + fr * 16 + quad * 4] = pack4(h4);
      }
    }
    short8 bv2[2];
    bv2[0] = *(const short8*)&vb[(size_t)l15 * SDIM + tok0 + quad * 8];
    bv2[1] = *(const short8*)&vb[(size_t)(16 + l15) * SDIM + tok0 + quad * 8];
#pragma unroll
    for (int mfr = 0; mfr < 8; ++mfr) {
      const short8 a2 = *(const short8*)&myphi[(mfr * 16 + l15) * 40 + quad * 8];
      cacc[mfr][0] = mfma16(a2, bv2[0], cacc[mfr][0]);
      cacc[mfr][1] = mfma16(a2, bv2[1], cacc[mfr][1]);
    }
  }
#pragma unroll
  for (int cf = 0; cf < 8; ++cf) {
    float v = ks_acc[cf];
    v += __shfl_xor(v, 16);
    v += __shfl_xor(v, 32);
    if (lane < 16) atomicAdd(&ksum[bh * 128 + cf * 16 + lane], v);
  }
  float* cb = ctx_acc + (size_t)bh * 4096;
#pragma unroll
  for (int mfr = 0; mfr < 8; ++mfr)
#pragma unroll
    for (int df = 0; df < 2; ++df)
#pragma unroll
      for (int r = 0; r < 4; ++r)
        atomicAdd(&cb[(mfr * 16 + quad * 4 + r) * 32 + df * 16 + l15], cacc[mfr][df][r]);
}

// Phase 2: phi_q via MFMA, out = phi_q@ctx * 1/denom; writes Y NHWC bf16
// via per-wave LDS transpose. ctx_finalize fused into ctx_s staging.
// grid = 512: bh(128) x quarter(4).
__global__ __launch_bounds__(256, 2)
void attn_phase2(const short* __restrict__ qq, const float* __restrict__ ctx_acc,
                 const float* __restrict__ ksum, const short* __restrict__ projb,
                 short* __restrict__ Yn) {
  __shared__ short proj_s[128 * 40];
  __shared__ short ctx_s[48 * 136];
  __shared__ short phi_s[4][32 * 136];
  const int tid = threadIdx.x;
  const int bh = blockIdx.x >> 2, qI = blockIdx.x & 3;
  for (int i = tid; i < 128 * 32; i += 256)
    proj_s[(i >> 5) * 40 + (i & 31)] = projb[i];
  {
    const float* ca = ctx_acc + (size_t)bh * 4096;
    const float* ks = ksum + bh * 128;
    for (int i = tid; i < 48 * 128; i += 256) {
      const int row = i >> 7, mf = i & 127;
      const float v = (row < 32) ? ca[mf * 32 + row] : ((row == 32) ? ks[mf] : 0.f);
      ctx_s[row * 136 + mf] = (short)f2bf(v);
    }
  }
  __syncthreads();
  const int lane = tid & 63, wv = tid >> 6;
  const int quad = lane >> 4, l15 = lane & 15;
  const int b = bh >> 3, head = bh & 7;
  const short* qb = qq + (size_t)bh * SDIM * DHEAD;
  short* myphi = phi_s[wv];
  const f32x4 vzero = {0.f, 0.f, 0.f, 0.f};

  for (int ch = qI * 4 + wv; ch < 98; ch += 16) {
    const int tok0 = ch * 32;
    short8 afr[2];
    afr[0] = *(const short8*)&qb[(size_t)(tok0 + l15) * DHEAD + quad * 8];
    afr[1] = *(const short8*)&qb[(size_t)(tok0 + 16 + l15) * DHEAD + quad * 8];
#pragma unroll
    for (int cf = 0; cf < 8; ++cf) {
      const short8 bfr = *(const short8*)&proj_s[(cf * 16 + l15) * 40 + quad * 8];
      const float epsv = (cf < 6) ? 1e-3f : ((cf == 6) ? ((l15 < 14) ? 1e-3f : 0.f) : 0.f);
#pragma unroll
      for (int fr = 0; fr < 2; ++fr) {
        f32x4 p = mfma16(afr[fr], bfr, vzero);
#pragma unroll
        for (int r = 0; r < 4; ++r) {
          const float pv = fmaxf(p[r], 0.f) + epsv;
          myphi[(fr * 16 + quad * 4 + r) * 136 + cf * 16 + l15] = (short)f2bf(pv);
        }
      }
    }
    f32x4 oacc[2][3];
#pragma unroll
    for (int fr = 0; fr < 2; ++fr)
#pragma unroll
      for (int c3 = 0; c3 < 3; ++c3) oacc[fr][c3] = vzero;
#pragma unroll
    for (int ksI = 0; ksI < 4; ++ksI) {
      short8 a3[2];
      a3[0] = *(const short8*)&myphi[l15 * 136 + ksI * 32 + quad * 8];
      a3[1] = *(const short8*)&myphi[(16 + l15) * 136 + ksI * 32 + quad * 8];
#pragma unroll
      for (int c3 = 0; c3 < 3; ++c3) {
        const short8 b3 = *(const short8*)&ctx_s[(c3 * 16 + l15) * 136 + ksI * 32 + quad * 8];
        oacc[0][c3] = mfma16(a3[0], b3, oacc[0][c3]);
        oacc[1][c3] = mfma16(a3[1], b3, oacc[1][c3]);
      }
    }
#pragma unroll
    for (int fr = 0; fr < 2; ++fr) {
      float dinv[4];
#pragma unroll
      for (int r = 0; r < 4; ++r) {
        const float den = __shfl(oacc[fr][2][r], quad << 4);
        dinv[r] = 1.f / den;
      }
#pragma unroll
      for (int c3 = 0; c3 < 2; ++c3)
#pragma unroll
        for (int r = 0; r < 4; ++r)
          myphi[(fr * 16 + quad * 4 + r) * 40 + c3 * 16 + l15] =
              (short)f2bf(oacc[fr][c3][r] * dinv[r]);
    }
    const size_t trow0 = (size_t)(b * SDIM + tok0) * 256 + head * 32;
#pragma unroll
    for (int it = 0; it < 2; ++it) {
      const int idx = it * 64 + lane;
      const int tl = idx >> 2, c4 = idx & 3;
      const short8 vv = *(const short8*)&myphi[tl * 40 + c4 * 8];
      *(short8*)&Yn[trow0 + (size_t)tl * 256 + c4 * 8] = vv;
    }
  }
}

// ---------------------------------------------------------------------------
// Wo GEMM: M=64, N=256 (grid 784). A = Y NHWC bf16, B = WoT packed.
// z = Y@Wo + bo + x (residual read directly from f32 NCHW x in the zt-write
// stage: per (cf,rf), 16 distinct 64B segments cover the wave). bn2 stats
// fused in the final write loop (fixed per-thread channel group).
__global__ __launch_bounds__(256, 4)
void wo_gemm(const short* __restrict__ Yn, const short* __restrict__ WoT,
             const float* __restrict__ bo, const float* __restrict__ x,
             short* __restrict__ z, float* __restrict__ sums) {
  __shared__ short A_s[64 * 264];  // staging pitch 256; epilogue zt pitch 264
  const int tid = threadIdx.x;
  const int mtile = blockIdx.x;
  const int token0 = mtile * 64;
  {
    const int trow = tid >> 5, cch = tid & 31;
    const short* src = Yn + (size_t)token0 * 256;
#pragma unroll
    for (int i = 0; i < 8; ++i) {
      const int tok = trow + i * 8;
      const short8 vv = *(const short8*)&src[tok * 256 + cch * 8];
      const int phys = cch ^ (tok & 31);
      *(short8*)&A_s[tok * 256 + phys * 8] = vv;
    }
  }
  __syncthreads();

  const int lane = tid & 63, wv = tid >> 6;
  const int quad = lane >> 4, l15 = lane & 15;
  const f32x4 vzero = {0.f, 0.f, 0.f, 0.f};
  f32x4 acc[4][4];
#pragma unroll
  for (int i = 0; i < 4; ++i)
#pragma unroll
    for (int j = 0; j < 4; ++j) acc[i][j] = vzero;
#pragma unroll
  for (int ks = 0; ks < 8; ++ks) {
    short8 af[4], bfr[4];
#pragma unroll
    for (int rf = 0; rf < 4; ++rf) {
      const int row = rf * 16 + l15;
      const int phys = (ks * 4 + quad) ^ (row & 31);
      af[rf] = *(const short8*)&A_s[row * 256 + phys * 8];
    }
#pragma unroll
    for (int cf = 0; cf < 4; ++cf)
      bfr[cf] = *(const short8*)&WoT[((((ks << 4) | (wv << 2) | cf) << 6) | lane) << 3];
#pragma unroll
    for (int rf = 0; rf < 4; ++rf)
#pragma unroll
      for (int cf = 0; cf < 4; ++cf)
        acc[rf][cf] = mfma16(af[rf], bfr[cf], acc[rf][cf]);
  }
  // epilogue: C-frag + bias + f32 x residual -> LDS [tok][oc], then coalesced
  // NHWC rows with fused bn2 stats.
  const int bb = token0 / SDIM;
  const int s0 = token0 - bb * SDIM;
  __syncthreads();
  short* zt = A_s;
#pragma unroll
  for (int cf = 0; cf < 4; ++cf) {
    const int ocl = wv * 64 + cf * 16 + l15;
    const float bias = bo[ocl];
#pragma unroll
    for (int rf = 0; rf < 4; ++rf) {
      const int tl = rf * 16 + quad * 4;
      const f32x4 xv = *(const f32x4*)(x + ((size_t)(bb * CDIM + ocl)) * SDIM + s0 + tl);
#pragma unroll
      for (int r = 0; r < 4; ++r)
        zt[(tl + r) * 264 + ocl] = (short)f2bf(acc[rf][cf][r] + bias + xv[r]);
    }
  }
  __syncthreads();
  float s[8], s2[8];
#pragma unroll
  for (int j = 0; j < 8; ++j) { s[j] = 0.f; s2[j] = 0.f; }
#pragma unroll
  for (int j = 0; j < 8; ++j) {
    const int idx = tid + j * 256;  // 0..2047
    const int tl = idx >> 5, ch = idx & 31;  // ch == tid & 31 (fixed per thread)
    const short8 zv = *(const short8*)&zt[tl * 264 + ch * 8];
#pragma unroll
    for (int jj = 0; jj < 8; ++jj) {
      const float f = bf2f(zv[jj]);
      s[jj] += f; s2[jj] += f * f;
    }
    *(short8*)&z[(size_t)(token0 + tl) * 256 + ch * 8] = zv;
  }
  // bn2 stats reduction (identical structure to old bn_stats_nhwc)
  __syncthreads();
  float* L = (float*)A_s;  // 256 x 16 floats = 16KB
#pragma unroll
  for (int j = 0; j < 8; ++j) { L[tid * 16 + j] = s[j]; L[tid * 16 + 8 + j] = s2[j]; }
  __syncthreads();
  const int c = tid, cgi = c >> 3, j2 = c & 7;
  float a = 0.f, b2 = 0.f;
#pragma unroll
  for (int tr = 0; tr < 8; ++tr) {
    a += L[(tr * 32 + cgi) * 16 + j2];
    b2 += L[(tr * 32 + cgi) * 16 + 8 + j2];
  }
  atomicAdd(&sums[c], a);
  atomicAdd(&sums[256 + c], b2);
}

// ---------------------------------------------------------------------------
// Conv 3x3 implicit GEMM (round-1 proven shape): M=32, N=256, grid 1568.
// Per dy band: stage 34(+6 pad) halo tokens once; dx taps = shifted LDS reads
// with per-lane boundary masks. Register prefetch of next dy overlaps compute.
__global__ __launch_bounds__(256, 4)
void conv_gemm(const short* __restrict__ u2, const short* __restrict__ Bc,
               const float* __restrict__ x, float* __restrict__ out) {
  __shared__ short A_s[40 * 256];  // 20.5 KB
  const int tid = threadIdx.x;
  // XCD-aware bijective swizzle: 1568 = 8 * 196.
  const int bid = blockIdx.x;
  const int mtile = (bid & 7) * 196 + (bid >> 3);
  const int bb = mtile / 98, s0 = (mtile - bb * 98) * 32;
  const short* ub = u2 + (size_t)bb * SDIM * 256;
  const int lane = tid & 63, wv = tid >> 6;
  const int quad = lane >> 4, l15 = lane & 15;
  const f32x4 vzero = {0.f, 0.f, 0.f, 0.f};
  const short8 szero = {0, 0, 0, 0, 0, 0, 0, 0};
  f32x4 acc[2][4];
#pragma unroll
  for (int i = 0; i < 2; ++i)
#pragma unroll
    for (int j = 0; j < 4; ++j) acc[i][j] = vzero;

  int vy[2], vx[2];
#pragma unroll
  for (int rf = 0; rf < 2; ++rf) {
    const int so = s0 + rf * 16 + l15;
    vy[rf] = so / 56;
    vx[rf] = so - vy[rf] * 56;
  }

  short8 pref[5];
#define LOAD_DY(DYI)                                                           \
  {                                                                            \
    const int srow0 = s0 + ((DYI)-1) * 56 - 1;                                 \
    _Pragma("unroll") for (int it = 0; it < 5; ++it) {                         \
      const int chunk = tid + it * 256;                                        \
      const int idx = chunk >> 5, cchl = chunk & 31;                           \
      const int s = srow0 + idx;                                               \
      short8 vv = {0, 0, 0, 0, 0, 0, 0, 0};                                    \
      if ((unsigned)s < (unsigned)SDIM)                                        \
        vv = *(const short8*)&ub[(size_t)s * 256 + cchl * 8];                  \
      pref[it] = vv;                                                           \
    }                                                                          \
  }

  LOAD_DY(0);
#pragma unroll
  for (int dyi = 0; dyi < 3; ++dyi) {
    if (dyi) __syncthreads();
#pragma unroll
    for (int it = 0; it < 5; ++it) {
      const int chunk = tid + it * 256;
      const int idx = chunk >> 5, cchl = chunk & 31;
      const int phys = cchl ^ (idx & 31);
      *(short8*)&A_s[idx * 256 + phys * 8] = pref[it];
    }
    __syncthreads();
    if (dyi < 2) LOAD_DY(dyi + 1);  // overlap next dy staging with compute
#pragma unroll
    for (int dxi = 0; dxi < 3; ++dxi) {
      const short* Bp = Bc + ((dyi * 3 + dxi) << 16);
      bool vmask[2];
#pragma unroll
      for (int rf = 0; rf < 2; ++rf)
        vmask[rf] = ((unsigned)(vy[rf] + dyi - 1) < 56u) &&
                    ((unsigned)(vx[rf] + dxi - 1) < 56u);
#pragma unroll
      for (int ks = 0; ks < 8; ++ks) {
        short8 af[2], bfr[4];
#pragma unroll
        for (int rf = 0; rf < 2; ++rf) {
          const int row = rf * 16 + l15 + dxi;  // shifted read = dx tap
          const int phys = (ks * 4 + quad) ^ (row & 31);
          const short8 a = *(const short8*)&A_s[row * 256 + phys * 8];
          af[rf] = vmask[rf] ? a : szero;
        }
#pragma unroll
        for (int cf = 0; cf < 4; ++cf)
          bfr[cf] = *(const short8*)&Bp[((((ks << 4) | (wv << 2) | cf) << 6) | lane) << 3];
#pragma unroll
        for (int rf = 0; rf < 2; ++rf)
#pragma unroll
          for (int cf = 0; cf < 4; ++cf)
            acc[rf][cf] = mfma16(af[rf], bfr[cf], acc[rf][cf]);
      }
    }
  }
#undef LOAD_DY

#pragma unroll
  for (int cf = 0; cf < 4; ++cf) {
    const int oc = wv * 64 + cf * 16 + l15;
#pragma unroll
    for (int rf = 0; rf < 2; ++rf) {
      const int ss = s0 + rf * 16 + quad * 4;
      const size_t base = ((size_t)(bb * CDIM + oc)) * SDIM + ss;
      const f32x4 xv = *(const f32x4*)(x + base);
      f32x4 res;
#pragma unroll
      for (int r = 0; r < 4; ++r) res[r] = acc[rf][cf][r] + xv[r];
      *(f32x4*)(out + base) = res;
    }
  }
}

// ---------------------------------------------------------------------------
extern "C" void kernel_launch(void* const* d_in, const int* in_sizes, int n_in,
                              void* d_out, int out_size, void* d_ws, size_t ws_size,
                              hipStream_t stream) {
  const float* x      = (const float*)d_in[0];
  const float* bn1_g  = (const float*)d_in[1];
  const float* bn1_b  = (const float*)d_in[2];
  const float* bn2_g  = (const float*)d_in[3];
  const float* bn2_b  = (const float*)d_in[4];
  const float* Wq     = (const float*)d_in[5];
  const float* bq     = (const float*)d_in[6];
  const float* Wk     = (const float*)d_in[7];
  const float* bk     = (const float*)d_in[8];
  const float* Wv     = (const float*)d_in[9];
  const float* bv     = (const float*)d_in[10];
  const float* Wo     = (const float*)d_in[11];
  const float* bo     = (const float*)d_in[12];
  const float* proj   = (const float*)d_in[13];
  const float* conv_w = (const float*)d_in[14];
  float* out = (float*)d_out;
  char* ws = (char*)d_ws;

  // ---- workspace layout ----
  const size_t OFF_K     = 0;           // bf16 k; then Y NHWC; then u2
  const size_t OFF_V     = 25690112;    // bf16 vT; then z NHWC
  const size_t OFF_BQKV  = 51380224;    // 393,216 B (packed)
  const size_t OFF_WOT   = 51773440;    // 131,072 B (packed)
  const size_t OFF_BCONV = 51904512;    // 1,179,648 B (packed)
  const size_t OFF_PROJB = 53084160;    // 8,192 B
  const size_t OFF_CTXA  = 53092352;    // 2,097,152 B
  const size_t OFF_KSUM  = 55189504;    // 65,536 B
  const size_t OFF_BN1S  = 55255040;    // 2,048 B
  const size_t OFF_BN2S  = 55257088;    // 2,048 B
  const size_t OFF_SC1   = 55259136;    // 2,048 B
  const size_t OFF_SC2   = 55261184;    // 2,048 B
  const size_t WS_NEEDED = 56836096;

  if (ws_size < WS_NEEDED) {
    zero_kernel<<<2048, 256, 0, stream>>>(out, out_size);
    return;
  }

  // d_out doubles as scratch: [q (25.7MB) | u1 (25.7MB)]
  short* qb    = (short*)d_out;
  short* u1b   = (short*)d_out + 12845056;
  short* kb    = (short*)(ws + OFF_K);
  short* vtb   = (short*)(ws + OFF_V);
  short* Yn    = (short*)(ws + OFF_K);
  short* zbuf  = (short*)(ws + OFF_V);
  short* u2b   = (short*)(ws + OFF_K);
  short* Bqkv  = (short*)(ws + OFF_BQKV);
  short* WoT   = (short*)(ws + OFF_WOT);
  short* Bconv = (short*)(ws + OFF_BCONV);
  short* projb = (short*)(ws + OFF_PROJB);
  float* ctxa  = (float*)(ws + OFF_CTXA);
  float* ksum  = (float*)(ws + OFF_KSUM);
  float* bn1s  = (float*)(ws + OFF_BN1S);
  float* bn2s  = (float*)(ws + OFF_BN2S);
  float* sc1   = (float*)(ws + OFF_SC1);
  float* sc2   = (float*)(ws + OFF_SC2);

  zero_kernel<<<512, 256, 0, stream>>>(ctxa, (2097152 + 65536 + 2048 + 2048) / 4);
  prep_kernel<<<256, 256, 0, stream>>>(Wq, Wk, Wv, Wo, proj, conv_w, Bqkv, WoT, Bconv, projb);
  bn_stats_kernel<<<4096, 256, 0, stream>>>(x, bn1s);
  bn_final_kernel<<<1, 256, 0, stream>>>(bn1s, bn1_g, bn1_b, sc1);
  transpose_x<<<dim3(784, 4), 256, 0, stream>>>(x, sc1, u1b);
  qkv_gemm<<<dim3(784, 3), 256, 0, stream>>>(u1b, Bqkv, bq, bk, bv, qb, kb, vtb);
  attn_phase1<<<512, 256, 0, stream>>>(kb, vtb, projb, ctxa, ksum);
  attn_phase2<<<512, 256, 0, stream>>>(qb, ctxa, ksum, projb, Yn);
  wo_gemm<<<784, 256, 0, stream>>>(Yn, WoT, bo, x, zbuf, bn2s);
  bn_final_kernel<<<1, 256, 0, stream>>>(bn2s, bn2_g, bn2_b, sc2);
  u2_kernel<<<1024, 256, 0, stream>>>(zbuf, sc2, u2b);
  conv_gemm<<<1568, 256, 0, stream>>>(u2b, Bconv, x, out);
}

// Round 12
// 457.256 us; speedup vs baseline: 1.0963x; 1.0059x over previous
//
#include <hip/hip_runtime.h>

// ---------------------------------------------------------------------------
// ACBlock: BN1+ReLU -> Performer attention -> +x -> BN2+ReLU -> conv3x3 -> +x
// B=16 C=256 H=W=56  S=3136 tokens/batch, NTOK=50176, heads=8, d=32, m=110
// Round 17 (from 460.0us best): qkv XCD-aware 1D grid (2352): the three sel
// blocks of one mtile get ids == xcd (mod 8) -> same XCD L2 -> A-tile fetched
// once not 3x (-51MB HBM). prep grid 512. Everything else = round-16 kernel.
// ---------------------------------------------------------------------------

typedef short short8 __attribute__((ext_vector_type(8)));
typedef float f32x4 __attribute__((ext_vector_type(4)));

#define DEVI static __device__ __forceinline__

#define CDIM 256
#define SDIM 3136
#define NTOK 50176
#define NHEAD 8
#define DHEAD 32
#define MFEAT 110
#define NORMC 0.42044820762685725f  // 32^-0.25
#define NPIX 50176.0f

DEVI unsigned short f2bf(float f) {
  union { float f; unsigned u; } v; v.f = f;
  unsigned r = v.u + 0x7fffu + ((v.u >> 16) & 1u);
  return (unsigned short)(r >> 16);
}

DEVI float bf2f(short h) {
  union { unsigned u; float f; } v;
  v.u = ((unsigned)(unsigned short)h) << 16;
  return v.f;
}

DEVI f32x4 mfma16(short8 a, short8 b, f32x4 c) {
  return __builtin_amdgcn_mfma_f32_16x16x32_bf16(a, b, c, 0, 0, 0);
}

DEVI unsigned long long pack4(const unsigned short* h) {
  return (unsigned long long)(h[0] | ((unsigned)h[1] << 16)) |
         ((unsigned long long)(h[2] | ((unsigned)h[3] << 16)) << 32);
}

// ---------------------------------------------------------------------------
__global__ void zero_kernel(float* p, int n) {
  for (int i = blockIdx.x * blockDim.x + threadIdx.x; i < n; i += gridDim.x * blockDim.x)
    p[i] = 0.f;
}

// Fragment-major packed B operands.
// Layout: packed[(ks*16 + nf)*512 + lane*8 + j] = B[n = nf*16 + (lane&15)]
//                                                  [k = ks*32 + (lane>>4)*8 + j]
__global__ void prep_kernel(const float* __restrict__ Wq, const float* __restrict__ Wk,
                            const float* __restrict__ Wv, const float* __restrict__ Wo,
                            const float* __restrict__ proj, const float* __restrict__ conv_w,
                            short* __restrict__ Bqkv, short* __restrict__ WoT,
                            short* __restrict__ Bconv, short* __restrict__ projb) {
  const int t0 = blockIdx.x * blockDim.x + threadIdx.x;
  const int stride = gridDim.x * blockDim.x;
  for (int idx = t0; idx < 3 * 65536; idx += stride) {
    const int sel = idx >> 16, r = idx & 65535;
    const int ks = r >> 13, nf = (r >> 9) & 15, lane = (r >> 3) & 63, j = r & 7;
    const int n = nf * 16 + (lane & 15), k = ks * 32 + (lane >> 4) * 8 + j;
    const float* W = (sel == 0) ? Wq : ((sel == 1) ? Wk : Wv);
    Bqkv[idx] = (short)f2bf(W[k * 256 + n]);
  }
  for (int idx = t0; idx < 65536; idx += stride) {
    const int ks = idx >> 13, nf = (idx >> 9) & 15, lane = (idx >> 3) & 63, j = idx & 7;
    const int n = nf * 16 + (lane & 15), k = ks * 32 + (lane >> 4) * 8 + j;
    WoT[idx] = (short)f2bf(Wo[k * 256 + n]);
  }
  for (int idx = t0; idx < 9 * 65536; idx += stride) {
    const int off = idx >> 16, r = idx & 65535;
    const int ks = r >> 13, nf = (r >> 9) & 15, lane = (r >> 3) & 63, j = r & 7;
    const int oc = nf * 16 + (lane & 15), cin = ks * 32 + (lane >> 4) * 8 + j;
    Bconv[idx] = (short)f2bf(conv_w[(oc * 256 + cin) * 9 + off]);
  }
  for (int idx = t0; idx < 128 * 32; idx += stride) {
    const int row = idx >> 5, kk = idx & 31;
    const float v = (row < MFEAT) ? proj[row * 32 + kk] * NORMC : 0.f;
    projb[idx] = (short)f2bf(v);
  }
}

// per-channel sum / sumsq over (B,H,W) for NCHW fp32 x; grid = B*C blocks
__global__ void bn_stats_kernel(const float* __restrict__ src, float* __restrict__ sums) {
  const int c = blockIdx.x & 255, b = blockIdx.x >> 8;
  const float* p = src + ((size_t)b * CDIM + c) * SDIM;
  float s = 0.f, s2 = 0.f;
  for (int i = threadIdx.x; i < SDIM; i += 256) {
    const float v = p[i];
    s += v; s2 += v * v;
  }
  for (int o = 32; o > 0; o >>= 1) { s += __shfl_down(s, o); s2 += __shfl_down(s2, o); }
  __shared__ float ls[4], ls2[4];
  const int w = threadIdx.x >> 6;
  if ((threadIdx.x & 63) == 0) { ls[w] = s; ls2[w] = s2; }
  __syncthreads();
  if (threadIdx.x == 0) {
    s = ls[0] + ls[1] + ls[2] + ls[3];
    s2 = ls2[0] + ls2[1] + ls2[2] + ls2[3];
    atomicAdd(&sums[c], s);
    atomicAdd(&sums[256 + c], s2);
  }
}

__global__ void bn_final_kernel(const float* __restrict__ sums, const float* __restrict__ gamma,
                                const float* __restrict__ beta, float* __restrict__ scsh) {
  const int c = threadIdx.x;
  const float mean = sums[c] * (1.f / NPIX);
  const float var = sums[256 + c] * (1.f / NPIX) - mean * mean;
  const float sc = gamma[c] * rsqrtf(var + 1e-5f);
  scsh[c] = sc;
  scsh[256 + c] = beta[c] - mean * sc;
}

// ---------------------------------------------------------------------------
// x NCHW f32 -> dst NHWC bf16 with relu(bn1) applied.
__global__ void transpose_x(const float* __restrict__ x, const float* __restrict__ scsh,
                            short* __restrict__ dst) {
  __shared__ short T[64][72];
  const int t0 = blockIdx.x * 64;
  const int b = t0 / SDIM;
  const int s0 = t0 - b * SDIM;
  const int c0 = blockIdx.y * 64;
  const int tid = threadIdx.x;
  const int tokl = tid & 63, cl = tid >> 6;
  const float* xb = x + ((size_t)b * CDIM + c0) * SDIM + s0;
#pragma unroll
  for (int i = 0; i < 16; ++i) {
    const int c = i * 4 + cl;
    float v = xb[(size_t)c * SDIM + tokl];
    v = fmaxf(v * scsh[c0 + c] + scsh[256 + c0 + c], 0.f);
    T[c][tokl] = (short)f2bf(v);
  }
  __syncthreads();
#pragma unroll
  for (int j = 0; j < 2; ++j) {
    const int idx = tid + j * 256;
    const int tk = idx >> 3, ch8 = idx & 7;
    unsigned short h[8];
#pragma unroll
    for (int jj = 0; jj < 8; ++jj) h[jj] = (unsigned short)T[ch8 * 8 + jj][tk];
    unsigned long long* p = (unsigned long long*)&dst[(size_t)(t0 + tk) * 256 + c0 + ch8 * 8];
    p[0] = pack4(h);
    p[1] = pack4(h + 4);
  }
}

// u2 = relu(bn2(z))  (NHWC bf16 elementwise)
__global__ void u2_kernel(const short* __restrict__ z, const float* __restrict__ scsh,
                          short* __restrict__ u2) {
  const int nchunks = NTOK * 32;
  for (int idx = blockIdx.x * blockDim.x + threadIdx.x; idx < nchunks;
       idx += gridDim.x * blockDim.x) {
    const int cch = idx & 31;
    const short8 v = *(const short8*)&z[(size_t)idx * 8];
    unsigned short h[8];
#pragma unroll
    for (int j = 0; j < 8; ++j) {
      const int c = cch * 8 + j;
      h[j] = f2bf(fmaxf(bf2f(v[j]) * scsh[c] + scsh[256 + c], 0.f));
    }
    unsigned long long* p = (unsigned long long*)&u2[(size_t)idx * 8];
    p[0] = pack4(h);
    p[1] = pack4(h + 4);
  }
}

// ---------------------------------------------------------------------------
// QKV GEMM: M=64, N=256 per block. 1D grid 2352, XCD-aware decomposition:
// xcd=bid&7, q=bid>>3, sel=q%3, mslot=q/3, mtile=xcd*98+mslot. The three sel
// blocks of one mtile share the XCD (ids differ by multiples of 8) and are
// dispatched within 24 ids -> A-tile is an L2 hit for sel=1,2.
// q/k epilogue: LDS transpose -> full 64B token rows (short8 stores).
// v epilogue: LDS transpose zt2[chn][tok] (pitch 66) -> 128B contiguous rows.
__global__ __launch_bounds__(256, 4)
void qkv_gemm(const short* __restrict__ u1, const short* __restrict__ BT,
              const float* __restrict__ bq, const float* __restrict__ bk,
              const float* __restrict__ bv,
              short* __restrict__ qo, short* __restrict__ ko, short* __restrict__ vo) {
  __shared__ short A_s[64 * 264];  // staging pitch 256; epilogues reuse
  const int tid = threadIdx.x;
  const int bid = blockIdx.x;
  const int xcd = bid & 7, qq2 = bid >> 3;
  const int sel = qq2 % 3, mslot = qq2 / 3;
  const int mtile = xcd * 98 + mslot;
  const int token0 = mtile * 64;
  {
    const int trow = tid >> 5, cch = tid & 31;
    const short* src = u1 + (size_t)token0 * 256;
#pragma unroll
    for (int i = 0; i < 8; ++i) {
      const int tok = trow + i * 8;
      const short8 vv = *(const short8*)&src[tok * 256 + cch * 8];
      const int phys = cch ^ (tok & 31);
      *(short8*)&A_s[tok * 256 + phys * 8] = vv;
    }
  }
  __syncthreads();

  const int lane = tid & 63, wv = tid >> 6;
  const int quad = lane >> 4, l15 = lane & 15;
  const f32x4 vzero = {0.f, 0.f, 0.f, 0.f};
  f32x4 acc[4][4];
#pragma unroll
  for (int i = 0; i < 4; ++i)
#pragma unroll
    for (int j = 0; j < 4; ++j) acc[i][j] = vzero;
  const short* Bp = BT + ((size_t)sel << 16);
#pragma unroll
  for (int ks = 0; ks < 8; ++ks) {
    short8 af[4], bfr[4];
#pragma unroll
    for (int rf = 0; rf < 4; ++rf) {
      const int row = rf * 16 + l15;
      const int phys = (ks * 4 + quad) ^ (row & 31);
      af[rf] = *(const short8*)&A_s[row * 256 + phys * 8];
    }
#pragma unroll
    for (int cf = 0; cf < 4; ++cf)
      bfr[cf] = *(const short8*)&Bp[((((ks << 4) | (wv << 2) | cf) << 6) | lane) << 3];
#pragma unroll
    for (int rf = 0; rf < 4; ++rf)
#pragma unroll
      for (int cf = 0; cf < 4; ++cf)
        acc[rf][cf] = mfma16(af[rf], bfr[cf], acc[rf][cf]);
  }

  const int bb = token0 / SDIM;
  const int s0 = token0 - bb * SDIM;  // batch-local token index
  if (sel < 2) {
    // LDS transpose epilogue: acc -> zt[tok][chn] (bias fused), then
    // coalesced short8 writes of full [tok][dd] rows.
    __syncthreads();
    short* zt = A_s;
#pragma unroll
    for (int cf = 0; cf < 4; ++cf) {
      const int chn = wv * 64 + cf * 16 + l15;
      const float bias = (sel == 0) ? bq[chn] : bk[chn];
#pragma unroll
      for (int rf = 0; rf < 4; ++rf) {
        const int tl = rf * 16 + quad * 4;
#pragma unroll
        for (int r = 0; r < 4; ++r)
          zt[(tl + r) * 264 + chn] = (short)f2bf(acc[rf][cf][r] + bias);
      }
    }
    __syncthreads();
    short* dst = (sel == 0) ? qo : ko;
#pragma unroll
    for (int j = 0; j < 8; ++j) {
      const int idx = tid + j * 256;  // 0..2047
      const int tl = idx >> 5, ch = idx & 31;  // ch = chn-group of 8
      const int head = ch >> 2, dd0 = (ch & 3) * 8;
      const short8 vv = *(const short8*)&zt[tl * 264 + ch * 8];
      *(short8*)&dst[((size_t)(bb * NHEAD + head) * SDIM + s0 + tl) * DHEAD + dd0] = vv;
    }
  } else {
    // v epilogue: zt2[chn][tok], pitch 66 (256*66 = 64*264 exactly).
    __syncthreads();
    short* zt = A_s;
#pragma unroll
    for (int cf = 0; cf < 4; ++cf) {
      const int chn = wv * 64 + cf * 16 + l15;
      const float bias = bv[chn];
#pragma unroll
      for (int rf = 0; rf < 4; ++rf) {
        const int tl = rf * 16 + quad * 4;
#pragma unroll
        for (int r = 0; r < 4; ++r)
          zt[chn * 66 + tl + r] = (short)f2bf(acc[rf][cf][r] + bias);
      }
    }
    __syncthreads();
#pragma unroll
    for (int j = 0; j < 8; ++j) {
      const int idx = tid + j * 256;  // 0..2047
      const int chn = idx >> 3, tch = (idx & 7) * 8;
      const int head = chn >> 5, dd = chn & 31;
      const short8 vv = *(const short8*)&zt[chn * 66 + tch];
      *(short8*)&vo[((size_t)(bb * NHEAD + head) * DHEAD + dd) * SDIM + s0 + tch] = vv;
    }
  }
}

// ---------------------------------------------------------------------------
// Phase 1: per (b,h): phi_k = relu(k @ projb^T)+eps via MFMA (K=32),
// LDS round-trip [mf][tok], then ctx[mf][d] += phi_k^T @ v, ksum[mf] += sums.
// grid = 512: bh(128) x quarter(4); (quarter,wave) owns ch residues mod 16.
__global__ __launch_bounds__(256, 2)
void attn_phase1(const short* __restrict__ kk, const short* __restrict__ vt,
                 const short* __restrict__ projb, float* __restrict__ ctx_acc,
                 float* __restrict__ ksum) {
  __shared__ short proj_s[128 * 40];
  __shared__ short phi_s[4][128 * 40];
  const int tid = threadIdx.x;
  const int bh = blockIdx.x >> 2, qI = blockIdx.x & 3;
  for (int i = tid; i < 128 * 32; i += 256)
    proj_s[(i >> 5) * 40 + (i & 31)] = projb[i];
  __syncthreads();
  const int lane = tid & 63, wv = tid >> 6;
  const int quad = lane >> 4, l15 = lane & 15;
  const short* kb = kk + (size_t)bh * SDIM * DHEAD;
  const short* vb = vt + (size_t)bh * DHEAD * SDIM;
  short* myphi = phi_s[wv];
  const f32x4 vzero = {0.f, 0.f, 0.f, 0.f};
  f32x4 cacc[8][2];
  float ks_acc[8];
#pragma unroll
  for (int i = 0; i < 8; ++i) { cacc[i][0] = vzero; cacc[i][1] = vzero; ks_acc[i] = 0.f; }

  for (int ch = qI * 4 + wv; ch < 98; ch += 16) {
    const int tok0 = ch * 32;
    short8 afr[2];
    afr[0] = *(const short8*)&kb[(size_t)(tok0 + l15) * DHEAD + quad * 8];
    afr[1] = *(const short8*)&kb[(size_t)(tok0 + 16 + l15) * DHEAD + quad * 8];
#pragma unroll
    for (int cf = 0; cf < 8; ++cf) {
      const short8 bfr = *(const short8*)&proj_s[(cf * 16 + l15) * 40 + quad * 8];
      const float epsv = (cf < 6) ? 1e-3f : ((cf == 6) ? ((l15 < 14) ? 1e-3f : 0.f) : 0.f);
#pragma unroll
      for (int fr = 0; fr < 2; ++fr) {
        f32x4 p = mfma16(afr[fr], bfr, vzero);
        unsigned short h4[4];
        float srow = 0.f;
#pragma unroll
        for (int r = 0; r < 4; ++r) {
          const float pv = fmaxf(p[r], 0.f) + epsv;
          srow += pv;
          h4[r] = f2bf(pv);
        }
        ks_acc[cf] += srow;
        *(unsigned long long*)&myphi[(cf * 16 + l15) * 40 + fr * 16 + quad * 4] = pack4(h4);
      }
    }
    short8 bv2[2];
    bv2[0] = *(const short8*)&vb[(size_t)l15 * SDIM + tok0 + quad * 8];
    bv2[1] = *(const short8*)&vb[(size_t)(16 + l15) * SDIM + tok0 + quad * 8];
#pragma unroll
    for (int mfr = 0; mfr < 8; ++mfr) {
      const short8 a2 = *(const short8*)&myphi[(mfr * 16 + l15) * 40 + quad * 8];
      cacc[mfr][0] = mfma16(a2, bv2[0], cacc[mfr][0]);
      cacc[mfr][1] = mfma16(a2, bv2[1], cacc[mfr][1]);
    }
  }
#pragma unroll
  for (int cf = 0; cf < 8; ++cf) {
    float v = ks_acc[cf];
    v += __shfl_xor(v, 16);
    v += __shfl_xor(v, 32);
    if (lane < 16) atomicAdd(&ksum[bh * 128 + cf * 16 + lane], v);
  }
  float* cb = ctx_acc + (size_t)bh * 4096;
#pragma unroll
  for (int mfr = 0; mfr < 8; ++mfr)
#pragma unroll
    for (int df = 0; df < 2; ++df)
#pragma unroll
      for (int r = 0; r < 4; ++r)
        atomicAdd(&cb[(mfr * 16 + quad * 4 + r) * 32 + df * 16 + l15], cacc[mfr][df][r]);
}

// Phase 2: phi_q via MFMA, out = phi_q@ctx * 1/denom; writes Y NHWC bf16
// via per-wave LDS transpose. ctx_finalize fused into ctx_s staging.
// grid = 512: bh(128) x quarter(4).
__global__ __launch_bounds__(256, 2)
void attn_phase2(const short* __restrict__ qq, const float* __restrict__ ctx_acc,
                 const float* __restrict__ ksum, const short* __restrict__ projb,
                 short* __restrict__ Yn) {
  __shared__ short proj_s[128 * 40];
  __shared__ short ctx_s[48 * 136];
  __shared__ short phi_s[4][32 * 136];
  const int tid = threadIdx.x;
  const int bh = blockIdx.x >> 2, qI = blockIdx.x & 3;
  for (int i = tid; i < 128 * 32; i += 256)
    proj_s[(i >> 5) * 40 + (i & 31)] = projb[i];
  {
    const float* ca = ctx_acc + (size_t)bh * 4096;
    const float* ks = ksum + bh * 128;
    for (int i = tid; i < 48 * 128; i += 256) {
      const int row = i >> 7, mf = i & 127;
      const float v = (row < 32) ? ca[mf * 32 + row] : ((row == 32) ? ks[mf] : 0.f);
      ctx_s[row * 136 + mf] = (short)f2bf(v);
    }
  }
  __syncthreads();
  const int lane = tid & 63, wv = tid >> 6;
  const int quad = lane >> 4, l15 = lane & 15;
  const int b = bh >> 3, head = bh & 7;
  const short* qb = qq + (size_t)bh * SDIM * DHEAD;
  short* myphi = phi_s[wv];
  const f32x4 vzero = {0.f, 0.f, 0.f, 0.f};

  for (int ch = qI * 4 + wv; ch < 98; ch += 16) {
    const int tok0 = ch * 32;
    short8 afr[2];
    afr[0] = *(const short8*)&qb[(size_t)(tok0 + l15) * DHEAD + quad * 8];
    afr[1] = *(const short8*)&qb[(size_t)(tok0 + 16 + l15) * DHEAD + quad * 8];
#pragma unroll
    for (int cf = 0; cf < 8; ++cf) {
      const short8 bfr = *(const short8*)&proj_s[(cf * 16 + l15) * 40 + quad * 8];
      const float epsv = (cf < 6) ? 1e-3f : ((cf == 6) ? ((l15 < 14) ? 1e-3f : 0.f) : 0.f);
#pragma unroll
      for (int fr = 0; fr < 2; ++fr) {
        f32x4 p = mfma16(afr[fr], bfr, vzero);
#pragma unroll
        for (int r = 0; r < 4; ++r) {
          const float pv = fmaxf(p[r], 0.f) + epsv;
          myphi[(fr * 16 + quad * 4 + r) * 136 + cf * 16 + l15] = (short)f2bf(pv);
        }
      }
    }
    f32x4 oacc[2][3];
#pragma unroll
    for (int fr = 0; fr < 2; ++fr)
#pragma unroll
      for (int c3 = 0; c3 < 3; ++c3) oacc[fr][c3] = vzero;
#pragma unroll
    for (int ksI = 0; ksI < 4; ++ksI) {
      short8 a3[2];
      a3[0] = *(const short8*)&myphi[l15 * 136 + ksI * 32 + quad * 8];
      a3[1] = *(const short8*)&myphi[(16 + l15) * 136 + ksI * 32 + quad * 8];
#pragma unroll
      for (int c3 = 0; c3 < 3; ++c3) {
        const short8 b3 = *(const short8*)&ctx_s[(c3 * 16 + l15) * 136 + ksI * 32 + quad * 8];
        oacc[0][c3] = mfma16(a3[0], b3, oacc[0][c3]);
        oacc[1][c3] = mfma16(a3[1], b3, oacc[1][c3]);
      }
    }
#pragma unroll
    for (int fr = 0; fr < 2; ++fr) {
      float dinv[4];
#pragma unroll
      for (int r = 0; r < 4; ++r) {
        const float den = __shfl(oacc[fr][2][r], quad << 4);
        dinv[r] = 1.f / den;
      }
#pragma unroll
      for (int c3 = 0; c3 < 2; ++c3)
#pragma unroll
        for (int r = 0; r < 4; ++r)
          myphi[(fr * 16 + quad * 4 + r) * 40 + c3 * 16 + l15] =
              (short)f2bf(oacc[fr][c3][r] * dinv[r]);
    }
    const size_t trow0 = (size_t)(b * SDIM + tok0) * 256 + head * 32;
#pragma unroll
    for (int it = 0; it < 2; ++it) {
      const int idx = it * 64 + lane;
      const int tl = idx >> 2, c4 = idx & 3;
      const short8 vv = *(const short8*)&myphi[tl * 40 + c4 * 8];
      *(short8*)&Yn[trow0 + (size_t)tl * 256 + c4 * 8] = vv;
    }
  }
}

// ---------------------------------------------------------------------------
// Wo GEMM: M=64, N=256 (grid 784). A = Y NHWC bf16, B = WoT packed.
// z = Y@Wo + bo + x (residual read directly from f32 NCHW x in the zt-write
// stage). bn2 stats fused in the final write loop.
__global__ __launch_bounds__(256, 4)
void wo_gemm(const short* __restrict__ Yn, const short* __restrict__ WoT,
             const float* __restrict__ bo, const float* __restrict__ x,
             short* __restrict__ z, float* __restrict__ sums) {
  __shared__ short A_s[64 * 264];  // staging pitch 256; epilogue zt pitch 264
  const int tid = threadIdx.x;
  const int mtile = blockIdx.x;
  const int token0 = mtile * 64;
  {
    const int trow = tid >> 5, cch = tid & 31;
    const short* src = Yn + (size_t)token0 * 256;
#pragma unroll
    for (int i = 0; i < 8; ++i) {
      const int tok = trow + i * 8;
      const short8 vv = *(const short8*)&src[tok * 256 + cch * 8];
      const int phys = cch ^ (tok & 31);
      *(short8*)&A_s[tok * 256 + phys * 8] = vv;
    }
  }
  __syncthreads();

  const int lane = tid & 63, wv = tid >> 6;
  const int quad = lane >> 4, l15 = lane & 15;
  const f32x4 vzero = {0.f, 0.f, 0.f, 0.f};
  f32x4 acc[4][4];
#pragma unroll
  for (int i = 0; i < 4; ++i)
#pragma unroll
    for (int j = 0; j < 4; ++j) acc[i][j] = vzero;
#pragma unroll
  for (int ks = 0; ks < 8; ++ks) {
    short8 af[4], bfr[4];
#pragma unroll
    for (int rf = 0; rf < 4; ++rf) {
      const int row = rf * 16 + l15;
      const int phys = (ks * 4 + quad) ^ (row & 31);
      af[rf] = *(const short8*)&A_s[row * 256 + phys * 8];
    }
#pragma unroll
    for (int cf = 0; cf < 4; ++cf)
      bfr[cf] = *(const short8*)&WoT[((((ks << 4) | (wv << 2) | cf) << 6) | lane) << 3];
#pragma unroll
    for (int rf = 0; rf < 4; ++rf)
#pragma unroll
      for (int cf = 0; cf < 4; ++cf)
        acc[rf][cf] = mfma16(af[rf], bfr[cf], acc[rf][cf]);
  }
  // epilogue: C-frag + bias + f32 x residual -> LDS [tok][oc], then coalesced
  // NHWC rows with fused bn2 stats.
  const int bb = token0 / SDIM;
  const int s0 = token0 - bb * SDIM;
  __syncthreads();
  short* zt = A_s;
#pragma unroll
  for (int cf = 0; cf < 4; ++cf) {
    const int ocl = wv * 64 + cf * 16 + l15;
    const float bias = bo[ocl];
#pragma unroll
    for (int rf = 0; rf < 4; ++rf) {
      const int tl = rf * 16 + quad * 4;
      const f32x4 xv = *(const f32x4*)(x + ((size_t)(bb * CDIM + ocl)) * SDIM + s0 + tl);
#pragma unroll
      for (int r = 0; r < 4; ++r)
        zt[(tl + r) * 264 + ocl] = (short)f2bf(acc[rf][cf][r] + bias + xv[r]);
    }
  }
  __syncthreads();
  float s[8], s2[8];
#pragma unroll
  for (int j = 0; j < 8; ++j) { s[j] = 0.f; s2[j] = 0.f; }
#pragma unroll
  for (int j = 0; j < 8; ++j) {
    const int idx = tid + j * 256;  // 0..2047
    const int tl = idx >> 5, ch = idx & 31;  // ch == tid & 31 (fixed per thread)
    const short8 zv = *(const short8*)&zt[tl * 264 + ch * 8];
#pragma unroll
    for (int jj = 0; jj < 8; ++jj) {
      const float f = bf2f(zv[jj]);
      s[jj] += f; s2[jj] += f * f;
    }
    *(short8*)&z[(size_t)(token0 + tl) * 256 + ch * 8] = zv;
  }
  // bn2 stats reduction (identical structure to old bn_stats_nhwc)
  __syncthreads();
  float* L = (float*)A_s;  // 256 x 16 floats = 16KB
#pragma unroll
  for (int j = 0; j < 8; ++j) { L[tid * 16 + j] = s[j]; L[tid * 16 + 8 + j] = s2[j]; }
  __syncthreads();
  const int c = tid, cgi = c >> 3, j2 = c & 7;
  float a = 0.f, b2 = 0.f;
#pragma unroll
  for (int tr = 0; tr < 8; ++tr) {
    a += L[(tr * 32 + cgi) * 16 + j2];
    b2 += L[(tr * 32 + cgi) * 16 + 8 + j2];
  }
  atomicAdd(&sums[c], a);
  atomicAdd(&sums[256 + c], b2);
}

// ---------------------------------------------------------------------------
// Conv 3x3 implicit GEMM (round-1 proven shape): M=32, N=256, grid 1568.
// Per dy band: stage 34(+6 pad) halo tokens once; dx taps = shifted LDS reads
// with per-lane boundary masks. Register prefetch of next dy overlaps compute.
__global__ __launch_bounds__(256, 4)
void conv_gemm(const short* __restrict__ u2, const short* __restrict__ Bc,
               const float* __restrict__ x, float* __restrict__ out) {
  __shared__ short A_s[40 * 256];  // 20.5 KB
  const int tid = threadIdx.x;
  // XCD-aware bijective swizzle: 1568 = 8 * 196.
  const int bid = blockIdx.x;
  const int mtile = (bid & 7) * 196 + (bid >> 3);
  const int bb = mtile / 98, s0 = (mtile - bb * 98) * 32;
  const short* ub = u2 + (size_t)bb * SDIM * 256;
  const int lane = tid & 63, wv = tid >> 6;
  const int quad = lane >> 4, l15 = lane & 15;
  const f32x4 vzero = {0.f, 0.f, 0.f, 0.f};
  const short8 szero = {0, 0, 0, 0, 0, 0, 0, 0};
  f32x4 acc[2][4];
#pragma unroll
  for (int i = 0; i < 2; ++i)
#pragma unroll
    for (int j = 0; j < 4; ++j) acc[i][j] = vzero;

  int vy[2], vx[2];
#pragma unroll
  for (int rf = 0; rf < 2; ++rf) {
    const int so = s0 + rf * 16 + l15;
    vy[rf] = so / 56;
    vx[rf] = so - vy[rf] * 56;
  }

  short8 pref[5];
#define LOAD_DY(DYI)                                                           \
  {                                                                            \
    const int srow0 = s0 + ((DYI)-1) * 56 - 1;                                 \
    _Pragma("unroll") for (int it = 0; it < 5; ++it) {                         \
      const int chunk = tid + it * 256;                                        \
      const int idx = chunk >> 5, cchl = chunk & 31;                           \
      const int s = srow0 + idx;                                               \
      short8 vv = {0, 0, 0, 0, 0, 0, 0, 0};                                    \
      if ((unsigned)s < (unsigned)SDIM)                                        \
        vv = *(const short8*)&ub[(size_t)s * 256 + cchl * 8];                  \
      pref[it] = vv;                                                           \
    }                                                                          \
  }

  LOAD_DY(0);
#pragma unroll
  for (int dyi = 0; dyi < 3; ++dyi) {
    if (dyi) __syncthreads();
#pragma unroll
    for (int it = 0; it < 5; ++it) {
      const int chunk = tid + it * 256;
      const int idx = chunk >> 5, cchl = chunk & 31;
      const int phys = cchl ^ (idx & 31);
      *(short8*)&A_s[idx * 256 + phys * 8] = pref[it];
    }
    __syncthreads();
    if (dyi < 2) LOAD_DY(dyi + 1);  // overlap next dy staging with compute
#pragma unroll
    for (int dxi = 0; dxi < 3; ++dxi) {
      const short* Bp = Bc + ((dyi * 3 + dxi) << 16);
      bool vmask[2];
#pragma unroll
      for (int rf = 0; rf < 2; ++rf)
        vmask[rf] = ((unsigned)(vy[rf] + dyi - 1) < 56u) &&
                    ((unsigned)(vx[rf] + dxi - 1) < 56u);
#pragma unroll
      for (int ks = 0; ks < 8; ++ks) {
        short8 af[2], bfr[4];
#pragma unroll
        for (int rf = 0; rf < 2; ++rf) {
          const int row = rf * 16 + l15 + dxi;  // shifted read = dx tap
          const int phys = (ks * 4 + quad) ^ (row & 31);
          const short8 a = *(const short8*)&A_s[row * 256 + phys * 8];
          af[rf] = vmask[rf] ? a : szero;
        }
#pragma unroll
        for (int cf = 0; cf < 4; ++cf)
          bfr[cf] = *(const short8*)&Bp[((((ks << 4) | (wv << 2) | cf) << 6) | lane) << 3];
#pragma unroll
        for (int rf = 0; rf < 2; ++rf)
#pragma unroll
          for (int cf = 0; cf < 4; ++cf)
            acc[rf][cf] = mfma16(af[rf], bfr[cf], acc[rf][cf]);
      }
    }
  }
#undef LOAD_DY

#pragma unroll
  for (int cf = 0; cf < 4; ++cf) {
    const int oc = wv * 64 + cf * 16 + l15;
#pragma unroll
    for (int rf = 0; rf < 2; ++rf) {
      const int ss = s0 + rf * 16 + quad * 4;
      const size_t base = ((size_t)(bb * CDIM + oc)) * SDIM + ss;
      const f32x4 xv = *(const f32x4*)(x + base);
      f32x4 res;
#pragma unroll
      for (int r = 0; r < 4; ++r) res[r] = acc[rf][cf][r] + xv[r];
      *(f32x4*)(out + base) = res;
    }
  }
}

// ---------------------------------------------------------------------------
extern "C" void kernel_launch(void* const* d_in, const int* in_sizes, int n_in,
                              void* d_out, int out_size, void* d_ws, size_t ws_size,
                              hipStream_t stream) {
  const float* x      = (const float*)d_in[0];
  const float* bn1_g  = (const float*)d_in[1];
  const float* bn1_b  = (const float*)d_in[2];
  const float* bn2_g  = (const float*)d_in[3];
  const float* bn2_b  = (const float*)d_in[4];
  const float* Wq     = (const float*)d_in[5];
  const float* bq     = (const float*)d_in[6];
  const float* Wk     = (const float*)d_in[7];
  const float* bk     = (const float*)d_in[8];
  const float* Wv     = (const float*)d_in[9];
  const float* bv     = (const float*)d_in[10];
  const float* Wo     = (const float*)d_in[11];
  const float* bo     = (const float*)d_in[12];
  const float* proj   = (const float*)d_in[13];
  const float* conv_w = (const float*)d_in[14];
  float* out = (float*)d_out;
  char* ws = (char*)d_ws;

  // ---- workspace layout ----
  const size_t OFF_K     = 0;           // bf16 k; then Y NHWC; then u2
  const size_t OFF_V     = 25690112;    // bf16 vT; then z NHWC
  const size_t OFF_BQKV  = 51380224;    // 393,216 B (packed)
  const size_t OFF_WOT   = 51773440;    // 131,072 B (packed)
  const size_t OFF_BCONV = 51904512;    // 1,179,648 B (packed)
  const size_t OFF_PROJB = 53084160;    // 8,192 B
  const size_t OFF_CTXA  = 53092352;    // 2,097,152 B
  const size_t OFF_KSUM  = 55189504;    // 65,536 B
  const size_t OFF_BN1S  = 55255040;    // 2,048 B
  const size_t OFF_BN2S  = 55257088;    // 2,048 B
  const size_t OFF_SC1   = 55259136;    // 2,048 B
  const size_t OFF_SC2   = 55261184;    // 2,048 B
  const size_t WS_NEEDED = 56836096;

  if (ws_size < WS_NEEDED) {
    zero_kernel<<<2048, 256, 0, stream>>>(out, out_size);
    return;
  }

  // d_out doubles as scratch: [q (25.7MB) | u1 (25.7MB)]
  short* qb    = (short*)d_out;
  short* u1b   = (short*)d_out + 12845056;
  short* kb    = (short*)(ws + OFF_K);
  short* vtb   = (short*)(ws + OFF_V);
  short* Yn    = (short*)(ws + OFF_K);
  short* zbuf  = (short*)(ws + OFF_V);
  short* u2b   = (short*)(ws + OFF_K);
  short* Bqkv  = (short*)(ws + OFF_BQKV);
  short* WoT   = (short*)(ws + OFF_WOT);
  short* Bconv = (short*)(ws + OFF_BCONV);
  short* projb = (short*)(ws + OFF_PROJB);
  float* ctxa  = (float*)(ws + OFF_CTXA);
  float* ksum  = (float*)(ws + OFF_KSUM);
  float* bn1s  = (float*)(ws + OFF_BN1S);
  float* bn2s  = (float*)(ws + OFF_BN2S);
  float* sc1   = (float*)(ws + OFF_SC1);
  float* sc2   = (float*)(ws + OFF_SC2);

  zero_kernel<<<512, 256, 0, stream>>>(ctxa, (2097152 + 65536 + 2048 + 2048) / 4);
  prep_kernel<<<512, 256, 0, stream>>>(Wq, Wk, Wv, Wo, proj, conv_w, Bqkv, WoT, Bconv, projb);
  bn_stats_kernel<<<4096, 256, 0, stream>>>(x, bn1s);
  bn_final_kernel<<<1, 256, 0, stream>>>(bn1s, bn1_g, bn1_b, sc1);
  transpose_x<<<dim3(784, 4), 256, 0, stream>>>(x, sc1, u1b);
  qkv_gemm<<<2352, 256, 0, stream>>>(u1b, Bqkv, bq, bk, bv, qb, kb, vtb);
  attn_phase1<<<512, 256, 0, stream>>>(kb, vtb, projb, ctxa, ksum);
  attn_phase2<<<512, 256, 0, stream>>>(qb, ctxa, ksum, projb, Yn);
  wo_gemm<<<784, 256, 0, stream>>>(Yn, WoT, bo, x, zbuf, bn2s);
  bn_final_kernel<<<1, 256, 0, stream>>>(bn2s, bn2_g, bn2_b, sc2);
  u2_kernel<<<1024, 256, 0, stream>>>(zbuf, sc2, u2b);
  conv_gemm<<<1568, 256, 0, stream>>>(u2b, Bconv, x, out);
}

// Round 13
// 455.368 us; speedup vs baseline: 1.1009x; 1.0041x over previous
//
#include <hip/hip_runtime.h>

// ---------------------------------------------------------------------------
// ACBlock: BN1+ReLU -> Performer attention -> +x -> BN2+ReLU -> conv3x3 -> +x
// B=16 C=256 H=W=56  S=3136 tokens/batch, NTOK=50176, heads=8, d=32, m=110
// Round 18 (from 457.3us best): attn_phase1 -> __launch_bounds__(256,3),
// isolated. LDS 50KB x 3 = 150KB <= 160KB; reg need ~110 < cap 170 (no
// spill). 3 blocks/CU = 12 waves/CU on the latency-bound phase-1.
// Everything else identical to the round-17 kernel.
// ---------------------------------------------------------------------------

typedef short short8 __attribute__((ext_vector_type(8)));
typedef float f32x4 __attribute__((ext_vector_type(4)));

#define DEVI static __device__ __forceinline__

#define CDIM 256
#define SDIM 3136
#define NTOK 50176
#define NHEAD 8
#define DHEAD 32
#define MFEAT 110
#define NORMC 0.42044820762685725f  // 32^-0.25
#define NPIX 50176.0f

DEVI unsigned short f2bf(float f) {
  union { float f; unsigned u; } v; v.f = f;
  unsigned r = v.u + 0x7fffu + ((v.u >> 16) & 1u);
  return (unsigned short)(r >> 16);
}

DEVI float bf2f(short h) {
  union { unsigned u; float f; } v;
  v.u = ((unsigned)(unsigned short)h) << 16;
  return v.f;
}

DEVI f32x4 mfma16(short8 a, short8 b, f32x4 c) {
  return __builtin_amdgcn_mfma_f32_16x16x32_bf16(a, b, c, 0, 0, 0);
}

DEVI unsigned long long pack4(const unsigned short* h) {
  return (unsigned long long)(h[0] | ((unsigned)h[1] << 16)) |
         ((unsigned long long)(h[2] | ((unsigned)h[3] << 16)) << 32);
}

// ---------------------------------------------------------------------------
__global__ void zero_kernel(float* p, int n) {
  for (int i = blockIdx.x * blockDim.x + threadIdx.x; i < n; i += gridDim.x * blockDim.x)
    p[i] = 0.f;
}

// Fragment-major packed B operands.
// Layout: packed[(ks*16 + nf)*512 + lane*8 + j] = B[n = nf*16 + (lane&15)]
//                                                  [k = ks*32 + (lane>>4)*8 + j]
__global__ void prep_kernel(const float* __restrict__ Wq, const float* __restrict__ Wk,
                            const float* __restrict__ Wv, const float* __restrict__ Wo,
                            const float* __restrict__ proj, const float* __restrict__ conv_w,
                            short* __restrict__ Bqkv, short* __restrict__ WoT,
                            short* __restrict__ Bconv, short* __restrict__ projb) {
  const int t0 = blockIdx.x * blockDim.x + threadIdx.x;
  const int stride = gridDim.x * blockDim.x;
  for (int idx = t0; idx < 3 * 65536; idx += stride) {
    const int sel = idx >> 16, r = idx & 65535;
    const int ks = r >> 13, nf = (r >> 9) & 15, lane = (r >> 3) & 63, j = r & 7;
    const int n = nf * 16 + (lane & 15), k = ks * 32 + (lane >> 4) * 8 + j;
    const float* W = (sel == 0) ? Wq : ((sel == 1) ? Wk : Wv);
    Bqkv[idx] = (short)f2bf(W[k * 256 + n]);
  }
  for (int idx = t0; idx < 65536; idx += stride) {
    const int ks = idx >> 13, nf = (idx >> 9) & 15, lane = (idx >> 3) & 63, j = idx & 7;
    const int n = nf * 16 + (lane & 15), k = ks * 32 + (lane >> 4) * 8 + j;
    WoT[idx] = (short)f2bf(Wo[k * 256 + n]);
  }
  for (int idx = t0; idx < 9 * 65536; idx += stride) {
    const int off = idx >> 16, r = idx & 65535;
    const int ks = r >> 13, nf = (r >> 9) & 15, lane = (r >> 3) & 63, j = r & 7;
    const int oc = nf * 16 + (lane & 15), cin = ks * 32 + (lane >> 4) * 8 + j;
    Bconv[idx] = (short)f2bf(conv_w[(oc * 256 + cin) * 9 + off]);
  }
  for (int idx = t0; idx < 128 * 32; idx += stride) {
    const int row = idx >> 5, kk = idx & 31;
    const float v = (row < MFEAT) ? proj[row * 32 + kk] * NORMC : 0.f;
    projb[idx] = (short)f2bf(v);
  }
}

// per-channel sum / sumsq over (B,H,W) for NCHW fp32 x; grid = B*C blocks
__global__ void bn_stats_kernel(const float* __restrict__ src, float* __restrict__ sums) {
  const int c = blockIdx.x & 255, b = blockIdx.x >> 8;
  const float* p = src + ((size_t)b * CDIM + c) * SDIM;
  float s = 0.f, s2 = 0.f;
  for (int i = threadIdx.x; i < SDIM; i += 256) {
    const float v = p[i];
    s += v; s2 += v * v;
  }
  for (int o = 32; o > 0; o >>= 1) { s += __shfl_down(s, o); s2 += __shfl_down(s2, o); }
  __shared__ float ls[4], ls2[4];
  const int w = threadIdx.x >> 6;
  if ((threadIdx.x & 63) == 0) { ls[w] = s; ls2[w] = s2; }
  __syncthreads();
  if (threadIdx.x == 0) {
    s = ls[0] + ls[1] + ls[2] + ls[3];
    s2 = ls2[0] + ls2[1] + ls2[2] + ls2[3];
    atomicAdd(&sums[c], s);
    atomicAdd(&sums[256 + c], s2);
  }
}

__global__ void bn_final_kernel(const float* __restrict__ sums, const float* __restrict__ gamma,
                                const float* __restrict__ beta, float* __restrict__ scsh) {
  const int c = threadIdx.x;
  const float mean = sums[c] * (1.f / NPIX);
  const float var = sums[256 + c] * (1.f / NPIX) - mean * mean;
  const float sc = gamma[c] * rsqrtf(var + 1e-5f);
  scsh[c] = sc;
  scsh[256 + c] = beta[c] - mean * sc;
}

// ---------------------------------------------------------------------------
// x NCHW f32 -> dst NHWC bf16 with relu(bn1) applied.
__global__ void transpose_x(const float* __restrict__ x, const float* __restrict__ scsh,
                            short* __restrict__ dst) {
  __shared__ short T[64][72];
  const int t0 = blockIdx.x * 64;
  const int b = t0 / SDIM;
  const int s0 = t0 - b * SDIM;
  const int c0 = blockIdx.y * 64;
  const int tid = threadIdx.x;
  const int tokl = tid & 63, cl = tid >> 6;
  const float* xb = x + ((size_t)b * CDIM + c0) * SDIM + s0;
#pragma unroll
  for (int i = 0; i < 16; ++i) {
    const int c = i * 4 + cl;
    float v = xb[(size_t)c * SDIM + tokl];
    v = fmaxf(v * scsh[c0 + c] + scsh[256 + c0 + c], 0.f);
    T[c][tokl] = (short)f2bf(v);
  }
  __syncthreads();
#pragma unroll
  for (int j = 0; j < 2; ++j) {
    const int idx = tid + j * 256;
    const int tk = idx >> 3, ch8 = idx & 7;
    unsigned short h[8];
#pragma unroll
    for (int jj = 0; jj < 8; ++jj) h[jj] = (unsigned short)T[ch8 * 8 + jj][tk];
    unsigned long long* p = (unsigned long long*)&dst[(size_t)(t0 + tk) * 256 + c0 + ch8 * 8];
    p[0] = pack4(h);
    p[1] = pack4(h + 4);
  }
}

// u2 = relu(bn2(z))  (NHWC bf16 elementwise)
__global__ void u2_kernel(const short* __restrict__ z, const float* __restrict__ scsh,
                          short* __restrict__ u2) {
  const int nchunks = NTOK * 32;
  for (int idx = blockIdx.x * blockDim.x + threadIdx.x; idx < nchunks;
       idx += gridDim.x * blockDim.x) {
    const int cch = idx & 31;
    const short8 v = *(const short8*)&z[(size_t)idx * 8];
    unsigned short h[8];
#pragma unroll
    for (int j = 0; j < 8; ++j) {
      const int c = cch * 8 + j;
      h[j] = f2bf(fmaxf(bf2f(v[j]) * scsh[c] + scsh[256 + c], 0.f));
    }
    unsigned long long* p = (unsigned long long*)&u2[(size_t)idx * 8];
    p[0] = pack4(h);
    p[1] = pack4(h + 4);
  }
}

// ---------------------------------------------------------------------------
// QKV GEMM: M=64, N=256 per block. 1D grid 2352, XCD-aware decomposition:
// xcd=bid&7, q=bid>>3, sel=q%3, mslot=q/3, mtile=xcd*98+mslot. The three sel
// blocks of one mtile share the XCD -> A-tile is an L2 hit for sel=1,2.
// q/k epilogue: LDS transpose -> full 64B token rows (short8 stores).
// v epilogue: LDS transpose zt2[chn][tok] (pitch 66) -> 128B contiguous rows.
__global__ __launch_bounds__(256, 4)
void qkv_gemm(const short* __restrict__ u1, const short* __restrict__ BT,
              const float* __restrict__ bq, const float* __restrict__ bk,
              const float* __restrict__ bv,
              short* __restrict__ qo, short* __restrict__ ko, short* __restrict__ vo) {
  __shared__ short A_s[64 * 264];  // staging pitch 256; epilogues reuse
  const int tid = threadIdx.x;
  const int bid = blockIdx.x;
  const int xcd = bid & 7, qq2 = bid >> 3;
  const int sel = qq2 % 3, mslot = qq2 / 3;
  const int mtile = xcd * 98 + mslot;
  const int token0 = mtile * 64;
  {
    const int trow = tid >> 5, cch = tid & 31;
    const short* src = u1 + (size_t)token0 * 256;
#pragma unroll
    for (int i = 0; i < 8; ++i) {
      const int tok = trow + i * 8;
      const short8 vv = *(const short8*)&src[tok * 256 + cch * 8];
      const int phys = cch ^ (tok & 31);
      *(short8*)&A_s[tok * 256 + phys * 8] = vv;
    }
  }
  __syncthreads();

  const int lane = tid & 63, wv = tid >> 6;
  const int quad = lane >> 4, l15 = lane & 15;
  const f32x4 vzero = {0.f, 0.f, 0.f, 0.f};
  f32x4 acc[4][4];
#pragma unroll
  for (int i = 0; i < 4; ++i)
#pragma unroll
    for (int j = 0; j < 4; ++j) acc[i][j] = vzero;
  const short* Bp = BT + ((size_t)sel << 16);
#pragma unroll
  for (int ks = 0; ks < 8; ++ks) {
    short8 af[4], bfr[4];
#pragma unroll
    for (int rf = 0; rf < 4; ++rf) {
      const int row = rf * 16 + l15;
      const int phys = (ks * 4 + quad) ^ (row & 31);
      af[rf] = *(const short8*)&A_s[row * 256 + phys * 8];
    }
#pragma unroll
    for (int cf = 0; cf < 4; ++cf)
      bfr[cf] = *(const short8*)&Bp[((((ks << 4) | (wv << 2) | cf) << 6) | lane) << 3];
#pragma unroll
    for (int rf = 0; rf < 4; ++rf)
#pragma unroll
      for (int cf = 0; cf < 4; ++cf)
        acc[rf][cf] = mfma16(af[rf], bfr[cf], acc[rf][cf]);
  }

  const int bb = token0 / SDIM;
  const int s0 = token0 - bb * SDIM;  // batch-local token index
  if (sel < 2) {
    __syncthreads();
    short* zt = A_s;
#pragma unroll
    for (int cf = 0; cf < 4; ++cf) {
      const int chn = wv * 64 + cf * 16 + l15;
      const float bias = (sel == 0) ? bq[chn] : bk[chn];
#pragma unroll
      for (int rf = 0; rf < 4; ++rf) {
        const int tl = rf * 16 + quad * 4;
#pragma unroll
        for (int r = 0; r < 4; ++r)
          zt[(tl + r) * 264 + chn] = (short)f2bf(acc[rf][cf][r] + bias);
      }
    }
    __syncthreads();
    short* dst = (sel == 0) ? qo : ko;
#pragma unroll
    for (int j = 0; j < 8; ++j) {
      const int idx = tid + j * 256;  // 0..2047
      const int tl = idx >> 5, ch = idx & 31;  // ch = chn-group of 8
      const int head = ch >> 2, dd0 = (ch & 3) * 8;
      const short8 vv = *(const short8*)&zt[tl * 264 + ch * 8];
      *(short8*)&dst[((size_t)(bb * NHEAD + head) * SDIM + s0 + tl) * DHEAD + dd0] = vv;
    }
  } else {
    // v epilogue: zt2[chn][tok], pitch 66 (256*66 = 64*264 exactly).
    __syncthreads();
    short* zt = A_s;
#pragma unroll
    for (int cf = 0; cf < 4; ++cf) {
      const int chn = wv * 64 + cf * 16 + l15;
      const float bias = bv[chn];
#pragma unroll
      for (int rf = 0; rf < 4; ++rf) {
        const int tl = rf * 16 + quad * 4;
#pragma unroll
        for (int r = 0; r < 4; ++r)
          zt[chn * 66 + tl + r] = (short)f2bf(acc[rf][cf][r] + bias);
      }
    }
    __syncthreads();
#pragma unroll
    for (int j = 0; j < 8; ++j) {
      const int idx = tid + j * 256;  // 0..2047
      const int chn = idx >> 3, tch = (idx & 7) * 8;
      const int head = chn >> 5, dd = chn & 31;
      const short8 vv = *(const short8*)&zt[chn * 66 + tch];
      *(short8*)&vo[((size_t)(bb * NHEAD + head) * DHEAD + dd) * SDIM + s0 + tch] = vv;
    }
  }
}

// ---------------------------------------------------------------------------
// Phase 1: per (b,h): phi_k = relu(k @ projb^T)+eps via MFMA (K=32),
// LDS round-trip [mf][tok], then ctx[mf][d] += phi_k^T @ v, ksum[mf] += sums.
// grid = 512: bh(128) x quarter(4). (256,3): 3 blocks/CU (LDS 150KB, regs
// ~110 < cap 170, no spill) on this latency-bound phase.
__global__ __launch_bounds__(256, 3)
void attn_phase1(const short* __restrict__ kk, const short* __restrict__ vt,
                 const short* __restrict__ projb, float* __restrict__ ctx_acc,
                 float* __restrict__ ksum) {
  __shared__ short proj_s[128 * 40];
  __shared__ short phi_s[4][128 * 40];
  const int tid = threadIdx.x;
  const int bh = blockIdx.x >> 2, qI = blockIdx.x & 3;
  for (int i = tid; i < 128 * 32; i += 256)
    proj_s[(i >> 5) * 40 + (i & 31)] = projb[i];
  __syncthreads();
  const int lane = tid & 63, wv = tid >> 6;
  const int quad = lane >> 4, l15 = lane & 15;
  const short* kb = kk + (size_t)bh * SDIM * DHEAD;
  const short* vb = vt + (size_t)bh * DHEAD * SDIM;
  short* myphi = phi_s[wv];
  const f32x4 vzero = {0.f, 0.f, 0.f, 0.f};
  f32x4 cacc[8][2];
  float ks_acc[8];
#pragma unroll
  for (int i = 0; i < 8; ++i) { cacc[i][0] = vzero; cacc[i][1] = vzero; ks_acc[i] = 0.f; }

  for (int ch = qI * 4 + wv; ch < 98; ch += 16) {
    const int tok0 = ch * 32;
    short8 afr[2];
    afr[0] = *(const short8*)&kb[(size_t)(tok0 + l15) * DHEAD + quad * 8];
    afr[1] = *(const short8*)&kb[(size_t)(tok0 + 16 + l15) * DHEAD + quad * 8];
#pragma unroll
    for (int cf = 0; cf < 8; ++cf) {
      const short8 bfr = *(const short8*)&proj_s[(cf * 16 + l15) * 40 + quad * 8];
      const float epsv = (cf < 6) ? 1e-3f : ((cf == 6) ? ((l15 < 14) ? 1e-3f : 0.f) : 0.f);
#pragma unroll
      for (int fr = 0; fr < 2; ++fr) {
        f32x4 p = mfma16(afr[fr], bfr, vzero);
        unsigned short h4[4];
        float srow = 0.f;
#pragma unroll
        for (int r = 0; r < 4; ++r) {
          const float pv = fmaxf(p[r], 0.f) + epsv;
          srow += pv;
          h4[r] = f2bf(pv);
        }
        ks_acc[cf] += srow;
        *(unsigned long long*)&myphi[(cf * 16 + l15) * 40 + fr * 16 + quad * 4] = pack4(h4);
      }
    }
    short8 bv2[2];
    bv2[0] = *(const short8*)&vb[(size_t)l15 * SDIM + tok0 + quad * 8];
    bv2[1] = *(const short8*)&vb[(size_t)(16 + l15) * SDIM + tok0 + quad * 8];
#pragma unroll
    for (int mfr = 0; mfr < 8; ++mfr) {
      const short8 a2 = *(const short8*)&myphi[(mfr * 16 + l15) * 40 + quad * 8];
      cacc[mfr][0] = mfma16(a2, bv2[0], cacc[mfr][0]);
      cacc[mfr][1] = mfma16(a2, bv2[1], cacc[mfr][1]);
    }
  }
#pragma unroll
  for (int cf = 0; cf < 8; ++cf) {
    float v = ks_acc[cf];
    v += __shfl_xor(v, 16);
    v += __shfl_xor(v, 32);
    if (lane < 16) atomicAdd(&ksum[bh * 128 + cf * 16 + lane], v);
  }
  float* cb = ctx_acc + (size_t)bh * 4096;
#pragma unroll
  for (int mfr = 0; mfr < 8; ++mfr)
#pragma unroll
    for (int df = 0; df < 2; ++df)
#pragma unroll
      for (int r = 0; r < 4; ++r)
        atomicAdd(&cb[(mfr * 16 + quad * 4 + r) * 32 + df * 16 + l15], cacc[mfr][df][r]);
}

// Phase 2: phi_q via MFMA, out = phi_q@ctx * 1/denom; writes Y NHWC bf16
// via per-wave LDS transpose. ctx_finalize fused into ctx_s staging.
// grid = 512: bh(128) x quarter(4).
__global__ __launch_bounds__(256, 2)
void attn_phase2(const short* __restrict__ qq, const float* __restrict__ ctx_acc,
                 const float* __restrict__ ksum, const short* __restrict__ projb,
                 short* __restrict__ Yn) {
  __shared__ short proj_s[128 * 40];
  __shared__ short ctx_s[48 * 136];
  __shared__ short phi_s[4][32 * 136];
  const int tid = threadIdx.x;
  const int bh = blockIdx.x >> 2, qI = blockIdx.x & 3;
  for (int i = tid; i < 128 * 32; i += 256)
    proj_s[(i >> 5) * 40 + (i & 31)] = projb[i];
  {
    const float* ca = ctx_acc + (size_t)bh * 4096;
    const float* ks = ksum + bh * 128;
    for (int i = tid; i < 48 * 128; i += 256) {
      const int row = i >> 7, mf = i & 127;
      const float v = (row < 32) ? ca[mf * 32 + row] : ((row == 32) ? ks[mf] : 0.f);
      ctx_s[row * 136 + mf] = (short)f2bf(v);
    }
  }
  __syncthreads();
  const int lane = tid & 63, wv = tid >> 6;
  const int quad = lane >> 4, l15 = lane & 15;
  const int b = bh >> 3, head = bh & 7;
  const short* qb = qq + (size_t)bh * SDIM * DHEAD;
  short* myphi = phi_s[wv];
  const f32x4 vzero = {0.f, 0.f, 0.f, 0.f};

  for (int ch = qI * 4 + wv; ch < 98; ch += 16) {
    const int tok0 = ch * 32;
    short8 afr[2];
    afr[0] = *(const short8*)&qb[(size_t)(tok0 + l15) * DHEAD + quad * 8];
    afr[1] = *(const short8*)&qb[(size_t)(tok0 + 16 + l15) * DHEAD + quad * 8];
#pragma unroll
    for (int cf = 0; cf < 8; ++cf) {
      const short8 bfr = *(const short8*)&proj_s[(cf * 16 + l15) * 40 + quad * 8];
      const float epsv = (cf < 6) ? 1e-3f : ((cf == 6) ? ((l15 < 14) ? 1e-3f : 0.f) : 0.f);
#pragma unroll
      for (int fr = 0; fr < 2; ++fr) {
        f32x4 p = mfma16(afr[fr], bfr, vzero);
#pragma unroll
        for (int r = 0; r < 4; ++r) {
          const float pv = fmaxf(p[r], 0.f) + epsv;
          myphi[(fr * 16 + quad * 4 + r) * 136 + cf * 16 + l15] = (short)f2bf(pv);
        }
      }
    }
    f32x4 oacc[2][3];
#pragma unroll
    for (int fr = 0; fr < 2; ++fr)
#pragma unroll
      for (int c3 = 0; c3 < 3; ++c3) oacc[fr][c3] = vzero;
#pragma unroll
    for (int ksI = 0; ksI < 4; ++ksI) {
      short8 a3[2];
      a3[0] = *(const short8*)&myphi[l15 * 136 + ksI * 32 + quad * 8];
      a3[1] = *(const short8*)&myphi[(16 + l15) * 136 + ksI * 32 + quad * 8];
#pragma unroll
      for (int c3 = 0; c3 < 3; ++c3) {
        const short8 b3 = *(const short8*)&ctx_s[(c3 * 16 + l15) * 136 + ksI * 32 + quad * 8];
        oacc[0][c3] = mfma16(a3[0], b3, oacc[0][c3]);
        oacc[1][c3] = mfma16(a3[1], b3, oacc[1][c3]);
      }
    }
#pragma unroll
    for (int fr = 0; fr < 2; ++fr) {
      float dinv[4];
#pragma unroll
      for (int r = 0; r < 4; ++r) {
        const float den = __shfl(oacc[fr][2][r], quad << 4);
        dinv[r] = 1.f / den;
      }
#pragma unroll
      for (int c3 = 0; c3 < 2; ++c3)
#pragma unroll
        for (int r = 0; r < 4; ++r)
          myphi[(fr * 16 + quad * 4 + r) * 40 + c3 * 16 + l15] =
              (short)f2bf(oacc[fr][c3][r] * dinv[r]);
    }
    const size_t trow0 = (size_t)(b * SDIM + tok0) * 256 + head * 32;
#pragma unroll
    for (int it = 0; it < 2; ++it) {
      const int idx = it * 64 + lane;
      const int tl = idx >> 2, c4 = idx & 3;
      const short8 vv = *(const short8*)&myphi[tl * 40 + c4 * 8];
      *(short8*)&Yn[trow0 + (size_t)tl * 256 + c4 * 8] = vv;
    }
  }
}

// ---------------------------------------------------------------------------
// Wo GEMM: M=64, N=256 (grid 784). A = Y NHWC bf16, B = WoT packed.
// z = Y@Wo + bo + x (residual read directly from f32 NCHW x in the zt-write
// stage). bn2 stats fused in the final write loop.
__global__ __launch_bounds__(256, 4)
void wo_gemm(const short* __restrict__ Yn, const short* __restrict__ WoT,
             const float* __restrict__ bo, const float* __restrict__ x,
             short* __restrict__ z, float* __restrict__ sums) {
  __shared__ short A_s[64 * 264];  // staging pitch 256; epilogue zt pitch 264
  const int tid = threadIdx.x;
  const int mtile = blockIdx.x;
  const int token0 = mtile * 64;
  {
    const int trow = tid >> 5, cch = tid & 31;
    const short* src = Yn + (size_t)token0 * 256;
#pragma unroll
    for (int i = 0; i < 8; ++i) {
      const int tok = trow + i * 8;
      const short8 vv = *(const short8*)&src[tok * 256 + cch * 8];
      const int phys = cch ^ (tok & 31);
      *(short8*)&A_s[tok * 256 + phys * 8] = vv;
    }
  }
  __syncthreads();

  const int lane = tid & 63, wv = tid >> 6;
  const int quad = lane >> 4, l15 = lane & 15;
  const f32x4 vzero = {0.f, 0.f, 0.f, 0.f};
  f32x4 acc[4][4];
#pragma unroll
  for (int i = 0; i < 4; ++i)
#pragma unroll
    for (int j = 0; j < 4; ++j) acc[i][j] = vzero;
#pragma unroll
  for (int ks = 0; ks < 8; ++ks) {
    short8 af[4], bfr[4];
#pragma unroll
    for (int rf = 0; rf < 4; ++rf) {
      const int row = rf * 16 + l15;
      const int phys = (ks * 4 + quad) ^ (row & 31);
      af[rf] = *(const short8*)&A_s[row * 256 + phys * 8];
    }
#pragma unroll
    for (int cf = 0; cf < 4; ++cf)
      bfr[cf] = *(const short8*)&WoT[((((ks << 4) | (wv << 2) | cf) << 6) | lane) << 3];
#pragma unroll
    for (int rf = 0; rf < 4; ++rf)
#pragma unroll
      for (int cf = 0; cf < 4; ++cf)
        acc[rf][cf] = mfma16(af[rf], bfr[cf], acc[rf][cf]);
  }
  // epilogue: C-frag + bias + f32 x residual -> LDS [tok][oc], then coalesced
  // NHWC rows with fused bn2 stats.
  const int bb = token0 / SDIM;
  const int s0 = token0 - bb * SDIM;
  __syncthreads();
  short* zt = A_s;
#pragma unroll
  for (int cf = 0; cf < 4; ++cf) {
    const int ocl = wv * 64 + cf * 16 + l15;
    const float bias = bo[ocl];
#pragma unroll
    for (int rf = 0; rf < 4; ++rf) {
      const int tl = rf * 16 + quad * 4;
      const f32x4 xv = *(const f32x4*)(x + ((size_t)(bb * CDIM + ocl)) * SDIM + s0 + tl);
#pragma unroll
      for (int r = 0; r < 4; ++r)
        zt[(tl + r) * 264 + ocl] = (short)f2bf(acc[rf][cf][r] + bias + xv[r]);
    }
  }
  __syncthreads();
  float s[8], s2[8];
#pragma unroll
  for (int j = 0; j < 8; ++j) { s[j] = 0.f; s2[j] = 0.f; }
#pragma unroll
  for (int j = 0; j < 8; ++j) {
    const int idx = tid + j * 256;  // 0..2047
    const int tl = idx >> 5, ch = idx & 31;  // ch == tid & 31 (fixed per thread)
    const short8 zv = *(const short8*)&zt[tl * 264 + ch * 8];
#pragma unroll
    for (int jj = 0; jj < 8; ++jj) {
      const float f = bf2f(zv[jj]);
      s[jj] += f; s2[jj] += f * f;
    }
    *(short8*)&z[(size_t)(token0 + tl) * 256 + ch * 8] = zv;
  }
  // bn2 stats reduction (identical structure to old bn_stats_nhwc)
  __syncthreads();
  float* L = (float*)A_s;  // 256 x 16 floats = 16KB
#pragma unroll
  for (int j = 0; j < 8; ++j) { L[tid * 16 + j] = s[j]; L[tid * 16 + 8 + j] = s2[j]; }
  __syncthreads();
  const int c = tid, cgi = c >> 3, j2 = c & 7;
  float a = 0.f, b2 = 0.f;
#pragma unroll
  for (int tr = 0; tr < 8; ++tr) {
    a += L[(tr * 32 + cgi) * 16 + j2];
    b2 += L[(tr * 32 + cgi) * 16 + 8 + j2];
  }
  atomicAdd(&sums[c], a);
  atomicAdd(&sums[256 + c], b2);
}

// ---------------------------------------------------------------------------
// Conv 3x3 implicit GEMM (round-1 proven shape): M=32, N=256, grid 1568.
// Per dy band: stage 34(+6 pad) halo tokens once; dx taps = shifted LDS reads
// with per-lane boundary masks. Register prefetch of next dy overlaps compute.
__global__ __launch_bounds__(256, 4)
void conv_gemm(const short* __restrict__ u2, const short* __restrict__ Bc,
               const float* __restrict__ x, float* __restrict__ out) {
  __shared__ short A_s[40 * 256];  // 20.5 KB
  const int tid = threadIdx.x;
  // XCD-aware bijective swizzle: 1568 = 8 * 196.
  const int bid = blockIdx.x;
  const int mtile = (bid & 7) * 196 + (bid >> 3);
  const int bb = mtile / 98, s0 = (mtile - bb * 98) * 32;
  const short* ub = u2 + (size_t)bb * SDIM * 256;
  const int lane = tid & 63, wv = tid >> 6;
  const int quad = lane >> 4, l15 = lane & 15;
  const f32x4 vzero = {0.f, 0.f, 0.f, 0.f};
  const short8 szero = {0, 0, 0, 0, 0, 0, 0, 0};
  f32x4 acc[2][4];
#pragma unroll
  for (int i = 0; i < 2; ++i)
#pragma unroll
    for (int j = 0; j < 4; ++j) acc[i][j] = vzero;

  int vy[2], vx[2];
#pragma unroll
  for (int rf = 0; rf < 2; ++rf) {
    const int so = s0 + rf * 16 + l15;
    vy[rf] = so / 56;
    vx[rf] = so - vy[rf] * 56;
  }

  short8 pref[5];
#define LOAD_DY(DYI)                                                           \
  {                                                                            \
    const int srow0 = s0 + ((DYI)-1) * 56 - 1;                                 \
    _Pragma("unroll") for (int it = 0; it < 5; ++it) {                         \
      const int chunk = tid + it * 256;                                        \
      const int idx = chunk >> 5, cchl = chunk & 31;                           \
      const int s = srow0 + idx;                                               \
      short8 vv = {0, 0, 0, 0, 0, 0, 0, 0};                                    \
      if ((unsigned)s < (unsigned)SDIM)                                        \
        vv = *(const short8*)&ub[(size_t)s * 256 + cchl * 8];                  \
      pref[it] = vv;                                                           \
    }                                                                          \
  }

  LOAD_DY(0);
#pragma unroll
  for (int dyi = 0; dyi < 3; ++dyi) {
    if (dyi) __syncthreads();
#pragma unroll
    for (int it = 0; it < 5; ++it) {
      const int chunk = tid + it * 256;
      const int idx = chunk >> 5, cchl = chunk & 31;
      const int phys = cchl ^ (idx & 31);
      *(short8*)&A_s[idx * 256 + phys * 8] = pref[it];
    }
    __syncthreads();
    if (dyi < 2) LOAD_DY(dyi + 1);  // overlap next dy staging with compute
#pragma unroll
    for (int dxi = 0; dxi < 3; ++dxi) {
      const short* Bp = Bc + ((dyi * 3 + dxi) << 16);
      bool vmask[2];
#pragma unroll
      for (int rf = 0; rf < 2; ++rf)
        vmask[rf] = ((unsigned)(vy[rf] + dyi - 1) < 56u) &&
                    ((unsigned)(vx[rf] + dxi - 1) < 56u);
#pragma unroll
      for (int ks = 0; ks < 8; ++ks) {
        short8 af[2], bfr[4];
#pragma unroll
        for (int rf = 0; rf < 2; ++rf) {
          const int row = rf * 16 + l15 + dxi;  // shifted read = dx tap
          const int phys = (ks * 4 + quad) ^ (row & 31);
          const short8 a = *(const short8*)&A_s[row * 256 + phys * 8];
          af[rf] = vmask[rf] ? a : szero;
        }
#pragma unroll
        for (int cf = 0; cf < 4; ++cf)
          bfr[cf] = *(const short8*)&Bp[((((ks << 4) | (wv << 2) | cf) << 6) | lane) << 3];
#pragma unroll
        for (int rf = 0; rf < 2; ++rf)
#pragma unroll
          for (int cf = 0; cf < 4; ++cf)
            acc[rf][cf] = mfma16(af[rf], bfr[cf], acc[rf][cf]);
      }
    }
  }
#undef LOAD_DY

#pragma unroll
  for (int cf = 0; cf < 4; ++cf) {
    const int oc = wv * 64 + cf * 16 + l15;
#pragma unroll
    for (int rf = 0; rf < 2; ++rf) {
      const int ss = s0 + rf * 16 + quad * 4;
      const size_t base = ((size_t)(bb * CDIM + oc)) * SDIM + ss;
      const f32x4 xv = *(const f32x4*)(x + base);
      f32x4 res;
#pragma unroll
      for (int r = 0; r < 4; ++r) res[r] = acc[rf][cf][r] + xv[r];
      *(f32x4*)(out + base) = res;
    }
  }
}

// ---------------------------------------------------------------------------
extern "C" void kernel_launch(void* const* d_in, const int* in_sizes, int n_in,
                              void* d_out, int out_size, void* d_ws, size_t ws_size,
                              hipStream_t stream) {
  const float* x      = (const float*)d_in[0];
  const float* bn1_g  = (const float*)d_in[1];
  const float* bn1_b  = (const float*)d_in[2];
  const float* bn2_g  = (const float*)d_in[3];
  const float* bn2_b  = (const float*)d_in[4];
  const float* Wq     = (const float*)d_in[5];
  const float* bq     = (const float*)d_in[6];
  const float* Wk     = (const float*)d_in[7];
  const float* bk     = (const float*)d_in[8];
  const float* Wv     = (const float*)d_in[9];
  const float* bv     = (const float*)d_in[10];
  const float* Wo     = (const float*)d_in[11];
  const float* bo     = (const float*)d_in[12];
  const float* proj   = (const float*)d_in[13];
  const float* conv_w = (const float*)d_in[14];
  float* out = (float*)d_out;
  char* ws = (char*)d_ws;

  // ---- workspace layout ----
  const size_t OFF_K     = 0;           // bf16 k; then Y NHWC; then u2
  const size_t OFF_V     = 25690112;    // bf16 vT; then z NHWC
  const size_t OFF_BQKV  = 51380224;    // 393,216 B (packed)
  const size_t OFF_WOT   = 51773440;    // 131,072 B (packed)
  const size_t OFF_BCONV = 51904512;    // 1,179,648 B (packed)
  const size_t OFF_PROJB = 53084160;    // 8,192 B
  const size_t OFF_CTXA  = 53092352;    // 2,097,152 B
  const size_t OFF_KSUM  = 55189504;    // 65,536 B
  const size_t OFF_BN1S  = 55255040;    // 2,048 B
  const size_t OFF_BN2S  = 55257088;    // 2,048 B
  const size_t OFF_SC1   = 55259136;    // 2,048 B
  const size_t OFF_SC2   = 55261184;    // 2,048 B
  const size_t WS_NEEDED = 56836096;

  if (ws_size < WS_NEEDED) {
    zero_kernel<<<2048, 256, 0, stream>>>(out, out_size);
    return;
  }

  // d_out doubles as scratch: [q (25.7MB) | u1 (25.7MB)]
  short* qb    = (short*)d_out;
  short* u1b   = (short*)d_out + 12845056;
  short* kb    = (short*)(ws + OFF_K);
  short* vtb   = (short*)(ws + OFF_V);
  short* Yn    = (short*)(ws + OFF_K);
  short* zbuf  = (short*)(ws + OFF_V);
  short* u2b   = (short*)(ws + OFF_K);
  short* Bqkv  = (short*)(ws + OFF_BQKV);
  short* WoT   = (short*)(ws + OFF_WOT);
  short* Bconv = (short*)(ws + OFF_BCONV);
  short* projb = (short*)(ws + OFF_PROJB);
  float* ctxa  = (float*)(ws + OFF_CTXA);
  float* ksum  = (float*)(ws + OFF_KSUM);
  float* bn1s  = (float*)(ws + OFF_BN1S);
  float* bn2s  = (float*)(ws + OFF_BN2S);
  float* sc1   = (float*)(ws + OFF_SC1);
  float* sc2   = (float*)(ws + OFF_SC2);

  zero_kernel<<<512, 256, 0, stream>>>(ctxa, (2097152 + 65536 + 2048 + 2048) / 4);
  prep_kernel<<<512, 256, 0, stream>>>(Wq, Wk, Wv, Wo, proj, conv_w, Bqkv, WoT, Bconv, projb);
  bn_stats_kernel<<<4096, 256, 0, stream>>>(x, bn1s);
  bn_final_kernel<<<1, 256, 0, stream>>>(bn1s, bn1_g, bn1_b, sc1);
  transpose_x<<<dim3(784, 4), 256, 0, stream>>>(x, sc1, u1b);
  qkv_gemm<<<2352, 256, 0, stream>>>(u1b, Bqkv, bq, bk, bv, qb, kb, vtb);
  attn_phase1<<<512, 256, 0, stream>>>(kb, vtb, projb, ctxa, ksum);
  attn_phase2<<<512, 256, 0, stream>>>(qb, ctxa, ksum, projb, Yn);
  wo_gemm<<<784, 256, 0, stream>>>(Yn, WoT, bo, x, zbuf, bn2s);
  bn_final_kernel<<<1, 256, 0, stream>>>(bn2s, bn2_g, bn2_b, sc2);
  u2_kernel<<<1024, 256, 0, stream>>>(zbuf, sc2, u2b);
  conv_gemm<<<1568, 256, 0, stream>>>(u2b, Bconv, x, out);
}